// Round 3
// baseline (91.878 us; speedup 1.0000x reference)
//
#include <hip/hip_runtime.h>
#include <hip/hip_bf16.h>

#define NN 2048
#define NH 12
#define HD 32
#define CALL 384   // NH*HD == OUT

typedef float f32x16 __attribute__((ext_vector_type(16)));
typedef _Float16 f16x4 __attribute__((ext_vector_type(4)));

static __device__ __forceinline__ f32x16 mfma8f16(f16x4 a, f16x4 b, f32x16 c) {
    return __builtin_amdgcn_mfma_f32_32x32x8f16(a, b, c, 0, 0, 0);
}

// ---------------------------------------------------------------------------
// GEMM-BT: out[m][n] = sum_k A[m][k] * B[n][k]   (both row-major, contract k)
// MODE 0: A=f32, write outT (f16, transposed [384][2048]), no bias   (h = x W^T)
// MODE 1: A=f32, write outF (f32 [M][384]) + bias                    (res)
// MODE 2: A=f16, write outF (f32 [M][384]) + bias + exact GELU       (final)
// ---------------------------------------------------------------------------
template <int MODE>
__global__ __launch_bounds__(256) void gemm_bt(
    const float* __restrict__ A, const _Float16* __restrict__ A16,
    const float* __restrict__ B, const float* __restrict__ bias,
    _Float16* __restrict__ outT, float* __restrict__ outF, int Kdim)
{
    __shared__ _Float16 As[64][36];
    __shared__ _Float16 Bs[64][36];
    const int t = threadIdx.x;
    const int w = t >> 6, l = t & 63, g = l >> 5, il = l & 31;
    const int m0 = blockIdx.x * 64, n0 = blockIdx.y * 64;
    const int wr = (w >> 1) * 32, wc = (w & 1) * 32;
    const int ti = t >> 2, seg = t & 3;

    f32x16 acc;
#pragma unroll
    for (int r = 0; r < 16; ++r) acc[r] = 0.f;

    for (int kk = 0; kk < Kdim; kk += 32) {
        __syncthreads();
        if (MODE == 2) {
            const uint4 v = *reinterpret_cast<const uint4*>(A16 + (size_t)(m0 + ti) * Kdim + kk + seg * 8);
            *reinterpret_cast<uint2*>(&As[ti][seg * 8])     = make_uint2(v.x, v.y);
            *reinterpret_cast<uint2*>(&As[ti][seg * 8 + 4]) = make_uint2(v.z, v.w);
        } else {
            const float* Ap = A + (size_t)(m0 + ti) * Kdim + kk + seg * 8;
            float4 v0 = *reinterpret_cast<const float4*>(Ap);
            float4 v1 = *reinterpret_cast<const float4*>(Ap + 4);
            f16x4 lo = {(_Float16)v0.x, (_Float16)v0.y, (_Float16)v0.z, (_Float16)v0.w};
            f16x4 hi = {(_Float16)v1.x, (_Float16)v1.y, (_Float16)v1.z, (_Float16)v1.w};
            *reinterpret_cast<f16x4*>(&As[ti][seg * 8])     = lo;
            *reinterpret_cast<f16x4*>(&As[ti][seg * 8 + 4]) = hi;
        }
        {
            const float* Bp = B + (size_t)(n0 + ti) * Kdim + kk + seg * 8;
            float4 v0 = *reinterpret_cast<const float4*>(Bp);
            float4 v1 = *reinterpret_cast<const float4*>(Bp + 4);
            f16x4 lo = {(_Float16)v0.x, (_Float16)v0.y, (_Float16)v0.z, (_Float16)v0.w};
            f16x4 hi = {(_Float16)v1.x, (_Float16)v1.y, (_Float16)v1.z, (_Float16)v1.w};
            *reinterpret_cast<f16x4*>(&Bs[ti][seg * 8])     = lo;
            *reinterpret_cast<f16x4*>(&Bs[ti][seg * 8 + 4]) = hi;
        }
        __syncthreads();
#pragma unroll
        for (int kc = 0; kc < 4; ++kc) {
            f16x4 af = *reinterpret_cast<const f16x4*>(&As[wr + il][kc * 8 + 4 * g]);
            f16x4 bf = *reinterpret_cast<const f16x4*>(&Bs[wc + il][kc * 8 + 4 * g]);
            acc = mfma8f16(af, bf, acc);
        }
    }

    const int colg = n0 + wc + il;
    if (MODE == 0) {
#pragma unroll
        for (int q = 0; q < 4; ++q) {
            const int row = m0 + wr + 8 * q + 4 * g;
            f16x4 v;
#pragma unroll
            for (int r = 0; r < 4; ++r) v[r] = (_Float16)acc[4 * q + r];
            *reinterpret_cast<f16x4*>(&outT[(size_t)colg * NN + row]) = v;
        }
    } else {
        const float bs = bias[colg];
#pragma unroll
        for (int reg = 0; reg < 16; ++reg) {
            const int row = m0 + wr + (reg & 3) + 8 * (reg >> 2) + 4 * g;
            float vv = acc[reg] + bs;
            if (MODE == 2) vv = 0.5f * vv * (1.0f + erff(vv * 0.70710678118f));
            outF[(size_t)row * CALL + colg] = vv;
        }
    }
}

// ---------------------------------------------------------------------------
// a_src[n][h] (row-major) and a_dstT[h][n] (transposed for attn staging)
// ---------------------------------------------------------------------------
__global__ __launch_bounds__(256) void srcdst_kernel(
    const _Float16* __restrict__ hT, const float* __restrict__ attn_src,
    const float* __restrict__ attn_dst, float* __restrict__ asrc, float* __restrict__ adstT)
{
    __shared__ float ssrc[CALL], sdst[CALL];
    const int t = threadIdx.x;
    for (int idx = t; idx < CALL; idx += 256) { ssrc[idx] = attn_src[idx]; sdst[idx] = attn_dst[idx]; }
    __syncthreads();
    const int n = blockIdx.x * 64 + (t & 63);
    const int q = t >> 6;  // heads 3q..3q+2
#pragma unroll
    for (int hh = 0; hh < 3; ++hh) {
        float a0 = 0.f, a1 = 0.f;
        for (int dd = 0; dd < 32; ++dd) {
            const int c = q * 96 + hh * 32 + dd;
            const float v = (float)hT[(size_t)c * NN + n];
            a0 = fmaf(v, ssrc[c], a0);
            a1 = fmaf(v, sdst[c], a1);
        }
        asrc[n * NH + q * 3 + hh] = a0;
        adstT[(size_t)(q * 3 + hh) * NN + n] = a1;
    }
}

// ---------------------------------------------------------------------------
// attn2: block = 32-row band x 3 heads. 8 waves, each owns a 256-col j-chunk.
// Wave-private LDS slices -> NO barriers in the tile loop (lgkm ordering
// within a wave suffices). Reg-prefetch of tile t+1 overlaps compute of t
// (T14 async-STAGE). Barriers only around the cross-wave reduction at end.
// ---------------------------------------------------------------------------
__global__ __launch_bounds__(512, 2) void attn2(
    const float* __restrict__ adj, const _Float16* __restrict__ hT,
    const float* __restrict__ asrc, const float* __restrict__ adstT,
    const float* __restrict__ eW, const float* __restrict__ eb,
    const float* __restrict__ res, _Float16* __restrict__ hsum)
{
    // per-wave slice at w*11904: adj[32][36] f32 (4608B) | hT[96][36] f16 (6912B) | adst[3][32] f32 (384B)
    // phase 2 (after barrier): red[8*3][16][64] f32 = 98304B overlaps slices; dsum_s at 98304 (3072B).
    __shared__ __align__(16) char smem[101376];
    const int t = threadIdx.x;
    const int w = t >> 6, l = t & 63, g = l >> 5, il = l & 31;
    const int band = blockIdx.x & 63, hg = blockIdx.x >> 6;
    const int i0 = band * 32, h0 = hg * 3, c0 = hg * 96;

    float (*adj_s)[36]   = (float(*)[36])(smem + w * 11904);
    _Float16 (*hT_s)[36] = (_Float16(*)[36])(smem + w * 11904 + 4608);
    float (*adst_s)[32]  = (float(*)[32])(smem + w * 11904 + 11520);
    float* red    = (float*)smem;
    float* dsum_s = (float*)(smem + 98304);

    float base_h[3], eWr[3];
#pragma unroll
    for (int hh = 0; hh < 3; ++hh) {
        base_h[hh] = asrc[(size_t)(i0 + il) * NH + h0 + hh] + eb[h0 + hh];
        eWr[hh] = eW[h0 + hh];
    }
    f32x16 acc[3];
#pragma unroll
    for (int hh = 0; hh < 3; ++hh)
#pragma unroll
        for (int r = 0; r < 16; ++r) acc[hh][r] = 0.f;
    float dsum[3] = {0.f, 0.f, 0.f};

    const int jbase = w * 256;

    // prefetch registers (single set; in-order issue handles WAR vs ds_write)
    float4 adjr[4];
    uint4  htr[6];
    float  ad0, ad1;

    auto LOAD = [&](int jb) {
#pragma unroll
        for (int p = 0; p < 4; ++p)
            adjr[p] = *reinterpret_cast<const float4*>(
                adj + (size_t)(i0 + p * 8 + (l >> 3)) * NN + jb + (l & 7) * 4);
#pragma unroll
        for (int p = 0; p < 6; ++p)
            htr[p] = *reinterpret_cast<const uint4*>(
                hT + (size_t)(c0 + p * 16 + (l >> 2)) * NN + jb + (l & 3) * 8);
        ad0 = adstT[(size_t)(h0 + (l >> 5)) * NN + jb + (l & 31)];
        ad1 = adstT[(size_t)(h0 + 2) * NN + jb + (l & 31)];
    };
    auto STORE = [&]() {
#pragma unroll
        for (int p = 0; p < 4; ++p)
            *reinterpret_cast<float4*>(&adj_s[p * 8 + (l >> 3)][(l & 7) * 4]) = adjr[p];
#pragma unroll
        for (int p = 0; p < 6; ++p) {
            *reinterpret_cast<uint2*>(&hT_s[p * 16 + (l >> 2)][(l & 3) * 8])     = make_uint2(htr[p].x, htr[p].y);
            *reinterpret_cast<uint2*>(&hT_s[p * 16 + (l >> 2)][(l & 3) * 8 + 4]) = make_uint2(htr[p].z, htr[p].w);
        }
        adst_s[l >> 5][l & 31] = ad0;
        if (l < 32) adst_s[2][l] = ad1;
    };

    LOAD(jbase);
    for (int tile = 0; tile < 8; ++tile) {
        STORE();
        if (tile < 7) LOAD(jbase + (tile + 1) * 32);   // overlap with compute below

#pragma unroll
        for (int ks = 0; ks < 4; ++ks) {
            const float4 aj = *reinterpret_cast<const float4*>(&adj_s[il][ks * 8 + 4 * g]);
#pragma unroll
            for (int hh = 0; hh < 3; ++hh) {
                f16x4 ef;
#pragma unroll
                for (int jj = 0; jj < 4; ++jj) {
                    const float ajv = (&aj.x)[jj];
                    const float ad_ = adst_s[hh][ks * 8 + 4 * g + jj];
                    float tt = fmaf(ajv, eWr[hh], base_h[hh] + ad_);
                    tt = fmaxf(tt, 0.2f * tt);
                    const float ee = ajv > 0.f ? exp2f(tt * 1.44269504089f) : 0.f;
                    dsum[hh] += ee;
                    ef[jj] = (_Float16)ee;
                }
                const f16x4 vf = *reinterpret_cast<const f16x4*>(&hT_s[hh * 32 + il][ks * 8 + 4 * g]);
                acc[hh] = mfma8f16(ef, vf, acc[hh]);
            }
        }
    }

    __syncthreads();   // all waves done reading their slices; red may overwrite
#pragma unroll
    for (int hh = 0; hh < 3; ++hh) {
        const float dtot = dsum[hh] + __shfl_xor(dsum[hh], 32);
        if (g == 0) dsum_s[(w * 3 + hh) * 32 + il] = dtot;
#pragma unroll
        for (int reg = 0; reg < 16; ++reg)
            red[((w * 3 + hh) * 16 + reg) * 64 + l] = acc[hh][reg];
    }
    __syncthreads();

#pragma unroll
    for (int rr = 0; rr < 2; ++rr) {
        const int reg = w + rr * 8;
        const int row_off = (reg & 3) + 8 * (reg >> 2) + 4 * g;
        const int row = i0 + row_off;
#pragma unroll
        for (int hh = 0; hh < 3; ++hh) {
            float v = 0.f, d = 0.f;
#pragma unroll
            for (int ww = 0; ww < 8; ++ww) {
                v += red[((ww * 3 + hh) * 16 + reg) * 64 + l];
                d += dsum_s[(ww * 3 + hh) * 32 + row_off];
            }
            const int col = (h0 + hh) * 32 + il;
            hsum[(size_t)row * CALL + col] = (_Float16)(v / d + res[(size_t)row * CALL + col]);
        }
    }
}

extern "C" void kernel_launch(void* const* d_in, const int* in_sizes, int n_in,
                              void* d_out, int out_size, void* d_ws, size_t ws_size,
                              hipStream_t stream)
{
    const float* x        = (const float*)d_in[0];
    const float* adj      = (const float*)d_in[1];
    const float* W        = (const float*)d_in[2];
    const float* attn_src = (const float*)d_in[3];
    const float* attn_dst = (const float*)d_in[4];
    const float* edge_W   = (const float*)d_in[5];
    const float* edge_b   = (const float*)d_in[6];
    const float* res_W    = (const float*)d_in[7];
    const float* res_b    = (const float*)d_in[8];
    const float* fus_W    = (const float*)d_in[9];
    const float* fus_b    = (const float*)d_in[10];
    float* out = (float*)d_out;

    char* ws = (char*)d_ws;
    size_t off = 0;
    auto alloc = [&](size_t bytes) { void* p = ws + off; off = (off + bytes + 255) & ~(size_t)255; return p; };
    _Float16* hT    = (_Float16*)alloc((size_t)CALL * NN * 2);
    float*    res   = (float*)alloc((size_t)NN * CALL * 4);
    float*    asrc  = (float*)alloc((size_t)NN * NH * 4);
    float*    adstT = (float*)alloc((size_t)NH * NN * 4);
    _Float16* hsum  = (_Float16*)alloc((size_t)NN * CALL * 2);
    (void)ws_size;

    dim3 blk(256);
    gemm_bt<0><<<dim3(32, 6), blk, 0, stream>>>(x, nullptr, W, nullptr, hT, nullptr, 256);
    gemm_bt<1><<<dim3(32, 6), blk, 0, stream>>>(x, nullptr, res_W, res_b, nullptr, res, 256);
    srcdst_kernel<<<32, blk, 0, stream>>>(hT, attn_src, attn_dst, asrc, adstT);
    attn2<<<256, dim3(512), 0, stream>>>(adj, hT, asrc, adstT, edge_W, edge_b, res, hsum);
    gemm_bt<2><<<dim3(32, 6), blk, 0, stream>>>(nullptr, hsum, fus_W, fus_b, nullptr, out, 384);
}

// Round 4
// 82.824 us; speedup vs baseline: 1.1093x; 1.1093x over previous
//
#include <hip/hip_runtime.h>
#include <hip/hip_bf16.h>

#define NN 2048
#define NH 12
#define HD 32
#define CALL 384   // NH*HD == OUT

typedef float f32x16 __attribute__((ext_vector_type(16)));
typedef _Float16 f16x4 __attribute__((ext_vector_type(4)));

static __device__ __forceinline__ f32x16 mfma8f16(f16x4 a, f16x4 b, f32x16 c) {
    return __builtin_amdgcn_mfma_f32_32x32x8f16(a, b, c, 0, 0, 0);
}

// ---------------------------------------------------------------------------
// GEMM-BT: out[m][n] = sum_k A[m][k] * B[n][k]   (both row-major, contract k)
// MODE 0: A=f32, write outT (f16, transposed [384][2048]), no bias   (h = x W^T)
// MODE 1: A=f32, write outF (f32 [M][384]) + bias                    (res)
// MODE 2: A=f16, write outF (f32 [M][384]) + bias + exact GELU       (final)
// ---------------------------------------------------------------------------
template <int MODE>
__global__ __launch_bounds__(256) void gemm_bt(
    const float* __restrict__ A, const _Float16* __restrict__ A16,
    const float* __restrict__ B, const float* __restrict__ bias,
    _Float16* __restrict__ outT, float* __restrict__ outF, int Kdim)
{
    __shared__ _Float16 As[64][36];
    __shared__ _Float16 Bs[64][36];
    const int t = threadIdx.x;
    const int w = t >> 6, l = t & 63, g = l >> 5, il = l & 31;
    const int m0 = blockIdx.x * 64, n0 = blockIdx.y * 64;
    const int wr = (w >> 1) * 32, wc = (w & 1) * 32;
    const int ti = t >> 2, seg = t & 3;

    f32x16 acc;
#pragma unroll
    for (int r = 0; r < 16; ++r) acc[r] = 0.f;

    for (int kk = 0; kk < Kdim; kk += 32) {
        __syncthreads();
        if (MODE == 2) {
            const uint4 v = *reinterpret_cast<const uint4*>(A16 + (size_t)(m0 + ti) * Kdim + kk + seg * 8);
            *reinterpret_cast<uint2*>(&As[ti][seg * 8])     = make_uint2(v.x, v.y);
            *reinterpret_cast<uint2*>(&As[ti][seg * 8 + 4]) = make_uint2(v.z, v.w);
        } else {
            const float* Ap = A + (size_t)(m0 + ti) * Kdim + kk + seg * 8;
            float4 v0 = *reinterpret_cast<const float4*>(Ap);
            float4 v1 = *reinterpret_cast<const float4*>(Ap + 4);
            f16x4 lo = {(_Float16)v0.x, (_Float16)v0.y, (_Float16)v0.z, (_Float16)v0.w};
            f16x4 hi = {(_Float16)v1.x, (_Float16)v1.y, (_Float16)v1.z, (_Float16)v1.w};
            *reinterpret_cast<f16x4*>(&As[ti][seg * 8])     = lo;
            *reinterpret_cast<f16x4*>(&As[ti][seg * 8 + 4]) = hi;
        }
        {
            const float* Bp = B + (size_t)(n0 + ti) * Kdim + kk + seg * 8;
            float4 v0 = *reinterpret_cast<const float4*>(Bp);
            float4 v1 = *reinterpret_cast<const float4*>(Bp + 4);
            f16x4 lo = {(_Float16)v0.x, (_Float16)v0.y, (_Float16)v0.z, (_Float16)v0.w};
            f16x4 hi = {(_Float16)v1.x, (_Float16)v1.y, (_Float16)v1.z, (_Float16)v1.w};
            *reinterpret_cast<f16x4*>(&Bs[ti][seg * 8])     = lo;
            *reinterpret_cast<f16x4*>(&Bs[ti][seg * 8 + 4]) = hi;
        }
        __syncthreads();
#pragma unroll
        for (int kc = 0; kc < 4; ++kc) {
            f16x4 af = *reinterpret_cast<const f16x4*>(&As[wr + il][kc * 8 + 4 * g]);
            f16x4 bf = *reinterpret_cast<const f16x4*>(&Bs[wc + il][kc * 8 + 4 * g]);
            acc = mfma8f16(af, bf, acc);
        }
    }

    const int colg = n0 + wc + il;
    if (MODE == 0) {
#pragma unroll
        for (int q = 0; q < 4; ++q) {
            const int row = m0 + wr + 8 * q + 4 * g;
            f16x4 v;
#pragma unroll
            for (int r = 0; r < 4; ++r) v[r] = (_Float16)acc[4 * q + r];
            *reinterpret_cast<f16x4*>(&outT[(size_t)colg * NN + row]) = v;
        }
    } else {
        const float bs = bias[colg];
#pragma unroll
        for (int reg = 0; reg < 16; ++reg) {
            const int row = m0 + wr + (reg & 3) + 8 * (reg >> 2) + 4 * g;
            float vv = acc[reg] + bs;
            if (MODE == 2) vv = 0.5f * vv * (1.0f + erff(vv * 0.70710678118f));
            outF[(size_t)row * CALL + colg] = vv;
        }
    }
}

// ---------------------------------------------------------------------------
// a_src[n][h] (row-major) and a_dstT[h][n] (transposed, PRE-SCALED by log2e)
// ---------------------------------------------------------------------------
__global__ __launch_bounds__(256) void srcdst_kernel(
    const _Float16* __restrict__ hT, const float* __restrict__ attn_src,
    const float* __restrict__ attn_dst, float* __restrict__ asrc, float* __restrict__ adstT)
{
    __shared__ float ssrc[CALL], sdst[CALL];
    const int t = threadIdx.x;
    for (int idx = t; idx < CALL; idx += 256) { ssrc[idx] = attn_src[idx]; sdst[idx] = attn_dst[idx]; }
    __syncthreads();
    const int n = blockIdx.x * 64 + (t & 63);
    const int q = t >> 6;  // heads 3q..3q+2
#pragma unroll
    for (int hh = 0; hh < 3; ++hh) {
        float a0 = 0.f, a1 = 0.f;
        for (int dd = 0; dd < 32; ++dd) {
            const int c = q * 96 + hh * 32 + dd;
            const float v = (float)hT[(size_t)c * NN + n];
            a0 = fmaf(v, ssrc[c], a0);
            a1 = fmaf(v, sdst[c], a1);
        }
        asrc[n * NH + q * 3 + hh] = a0;
        adstT[(size_t)(q * 3 + hh) * NN + n] = a1 * 1.44269504089f;
    }
}

// ---------------------------------------------------------------------------
// attn3: block = 32-row band x 3 heads. 8 waves, each owns a 256-col j-chunk.
// hT tile in wave-private LDS (no barriers in main loop); adj read per-lane
// direct from global (L1 catches ks-pair line reuse); adst read as broadcast
// float4 from global (L2). Epilogue: 3 barriers, 4-wave red region (49KB)
// overlaying dead staging slices -> LDS 60KB -> 2 blocks/CU.
// ---------------------------------------------------------------------------
__global__ __launch_bounds__(512) void attn3(
    const float* __restrict__ adj, const _Float16* __restrict__ hT,
    const float* __restrict__ asrc, const float* __restrict__ adstT,
    const float* __restrict__ eW, const float* __restrict__ eb,
    const float* __restrict__ res, _Float16* __restrict__ hsum)
{
    // staging: per-wave slice w*7680: hT_s[96][40] f16 (rows padded to 80B for b128 writes)
    // epilogue overlay: red[4][3][16][64] f32 at 0 (49152B) | dsum_s[8][3][32] at 49152 (3072B)
    __shared__ __align__(16) char smem[61440];
    const int t = threadIdx.x;
    const int w = t >> 6, l = t & 63, g = l >> 5, il = l & 31;
    const int band = blockIdx.x & 63, hg = blockIdx.x >> 6;
    const int i0 = band * 32, h0 = hg * 3, c0 = hg * 96;

    _Float16 (*hT_s)[40] = (_Float16(*)[40])(smem + w * 7680);
    float* red    = (float*)smem;
    float* dsum_s = (float*)(smem + 49152);

    const float LOG2E = 1.44269504089f;
    float base_h[3], eWr[3];
#pragma unroll
    for (int hh = 0; hh < 3; ++hh) {
        base_h[hh] = (asrc[(size_t)(i0 + il) * NH + h0 + hh] + eb[h0 + hh]) * LOG2E;
        eWr[hh] = eW[h0 + hh] * LOG2E;
    }
    f32x16 acc[3];
#pragma unroll
    for (int hh = 0; hh < 3; ++hh)
#pragma unroll
        for (int r = 0; r < 16; ++r) acc[hh][r] = 0.f;
    float dsum[3] = {0.f, 0.f, 0.f};

    const int jbase = w * 256;
    for (int tile = 0; tile < 8; ++tile) {
        const int jb = jbase + tile * 32;
        // stage hT 96x32 f16 (wave-private; no block barrier needed)
#pragma unroll
        for (int p = 0; p < 6; ++p) {
            const int r = p * 16 + (l >> 2), s = (l & 3) * 8;
            const uint4 v = *reinterpret_cast<const uint4*>(hT + (size_t)(c0 + r) * NN + jb + s);
            *reinterpret_cast<uint4*>(&hT_s[r][s]) = v;
        }
        // adj: per-lane direct loads (row il), 4x float4
        float4 aj0 = *reinterpret_cast<const float4*>(adj + (size_t)(i0 + il) * NN + jb + 0 * 8 + 4 * g);
        float4 aj1 = *reinterpret_cast<const float4*>(adj + (size_t)(i0 + il) * NN + jb + 1 * 8 + 4 * g);
        float4 aj2 = *reinterpret_cast<const float4*>(adj + (size_t)(i0 + il) * NN + jb + 2 * 8 + 4 * g);
        float4 aj3 = *reinterpret_cast<const float4*>(adj + (size_t)(i0 + il) * NN + jb + 3 * 8 + 4 * g);

#pragma unroll
        for (int ks = 0; ks < 4; ++ks) {
            const float4 aj = (ks == 0) ? aj0 : (ks == 1) ? aj1 : (ks == 2) ? aj2 : aj3;
#pragma unroll
            for (int hh = 0; hh < 3; ++hh) {
                // adst: broadcast float4 from global (L2-hit), pre-scaled by log2e
                const float4 ad = *reinterpret_cast<const float4*>(
                    adstT + (size_t)(h0 + hh) * NN + jb + ks * 8 + 4 * g);
                f16x4 ef;
#pragma unroll
                for (int jj = 0; jj < 4; ++jj) {
                    const float ajv = (&aj.x)[jj];
                    float tt = fmaf(ajv, eWr[hh], base_h[hh] + (&ad.x)[jj]);
                    tt = fmaxf(tt, 0.2f * tt);
                    const float ee = ajv > 0.f ? exp2f(tt) : 0.f;
                    dsum[hh] += ee;
                    ef[jj] = (_Float16)ee;
                }
                const f16x4 vf = *reinterpret_cast<const f16x4*>(&hT_s[hh * 32 + il][ks * 8 + 4 * g]);
                acc[hh] = mfma8f16(ef, vf, acc[hh]);
            }
        }
    }

    // ---- epilogue: cross-wave reduce via 4-wave red region (3 barriers) ----
    __syncthreads();   // all waves done with their staging slices
#pragma unroll
    for (int hh = 0; hh < 3; ++hh) {
        const float dtot = dsum[hh] + __shfl_xor(dsum[hh], 32);
        if (g == 0) dsum_s[(w * 3 + hh) * 32 + il] = dtot;
    }
    if (w < 4) {
#pragma unroll
        for (int hh = 0; hh < 3; ++hh)
#pragma unroll
            for (int reg = 0; reg < 16; ++reg)
                red[((w * 3 + hh) * 16 + reg) * 64 + l] = acc[hh][reg];
    }
    __syncthreads();
    if (w >= 4) {
#pragma unroll
        for (int hh = 0; hh < 3; ++hh)
#pragma unroll
            for (int reg = 0; reg < 16; ++reg)
                red[(((w - 4) * 3 + hh) * 16 + reg) * 64 + l] += acc[hh][reg];
    }
    __syncthreads();

#pragma unroll
    for (int rr = 0; rr < 2; ++rr) {
        const int reg = w + rr * 8;
        const int row_off = (reg & 3) + 8 * (reg >> 2) + 4 * g;
        const int row = i0 + row_off;
#pragma unroll
        for (int hh = 0; hh < 3; ++hh) {
            float v = 0.f, d = 0.f;
#pragma unroll
            for (int ww = 0; ww < 4; ++ww)
                v += red[((ww * 3 + hh) * 16 + reg) * 64 + l];
#pragma unroll
            for (int ww = 0; ww < 8; ++ww)
                d += dsum_s[(ww * 3 + hh) * 32 + row_off];
            const int col = (h0 + hh) * 32 + il;
            hsum[(size_t)row * CALL + col] = (_Float16)(v / d + res[(size_t)row * CALL + col]);
        }
    }
}

extern "C" void kernel_launch(void* const* d_in, const int* in_sizes, int n_in,
                              void* d_out, int out_size, void* d_ws, size_t ws_size,
                              hipStream_t stream)
{
    const float* x        = (const float*)d_in[0];
    const float* adj      = (const float*)d_in[1];
    const float* W        = (const float*)d_in[2];
    const float* attn_src = (const float*)d_in[3];
    const float* attn_dst = (const float*)d_in[4];
    const float* edge_W   = (const float*)d_in[5];
    const float* edge_b   = (const float*)d_in[6];
    const float* res_W    = (const float*)d_in[7];
    const float* res_b    = (const float*)d_in[8];
    const float* fus_W    = (const float*)d_in[9];
    const float* fus_b    = (const float*)d_in[10];
    float* out = (float*)d_out;

    char* ws = (char*)d_ws;
    size_t off = 0;
    auto alloc = [&](size_t bytes) { void* p = ws + off; off = (off + bytes + 255) & ~(size_t)255; return p; };
    _Float16* hT    = (_Float16*)alloc((size_t)CALL * NN * 2);
    float*    res   = (float*)alloc((size_t)NN * CALL * 4);
    float*    asrc  = (float*)alloc((size_t)NN * NH * 4);
    float*    adstT = (float*)alloc((size_t)NH * NN * 4);
    _Float16* hsum  = (_Float16*)alloc((size_t)NN * CALL * 2);
    (void)ws_size;

    dim3 blk(256);
    gemm_bt<0><<<dim3(32, 6), blk, 0, stream>>>(x, nullptr, W, nullptr, hT, nullptr, 256);
    gemm_bt<1><<<dim3(32, 6), blk, 0, stream>>>(x, nullptr, res_W, res_b, nullptr, res, 256);
    srcdst_kernel<<<32, blk, 0, stream>>>(hT, attn_src, attn_dst, asrc, adstT);
    attn3<<<256, dim3(512), 0, stream>>>(adj, hT, asrc, adstT, edge_W, edge_b, res, hsum);
    gemm_bt<2><<<dim3(32, 6), blk, 0, stream>>>(nullptr, hsum, fus_W, fus_b, nullptr, out, 384);
}

// Round 5
// 61.960 us; speedup vs baseline: 1.4829x; 1.3367x over previous
//
#include <hip/hip_runtime.h>
#include <hip/hip_bf16.h>

#define NN 2048
#define NH 12
#define HD 32
#define CALL 384   // NH*HD == OUT

typedef float f32x16 __attribute__((ext_vector_type(16)));
typedef _Float16 f16x4 __attribute__((ext_vector_type(4)));

static __device__ __forceinline__ f32x16 mfma8f16(f16x4 a, f16x4 b, f32x16 c) {
    return __builtin_amdgcn_mfma_f32_32x32x8f16(a, b, c, 0, 0, 0);
}

// ---------------------------------------------------------------------------
// gemm01: fused first two GEMMs (share A = x, K=256).
// z=0: h = x W^T      -> outT (f16, transposed [384][2048])
// z=1: res = x resW^T -> outF (f32 [2048][384]) + bias
// ---------------------------------------------------------------------------
__global__ __launch_bounds__(256) void gemm01(
    const float* __restrict__ A, const float* __restrict__ B0,
    const float* __restrict__ B1, const float* __restrict__ bias1,
    _Float16* __restrict__ outT, float* __restrict__ outF)
{
    __shared__ _Float16 As[64][36];
    __shared__ _Float16 Bs[64][36];
    const int t = threadIdx.x;
    const int w = t >> 6, l = t & 63, g = l >> 5, il = l & 31;
    const int m0 = blockIdx.x * 64, n0 = blockIdx.y * 64;
    const int mode = blockIdx.z;
    const float* B = mode ? B1 : B0;
    const int wr = (w >> 1) * 32, wc = (w & 1) * 32;
    const int ti = t >> 2, seg = t & 3;
    const int Kdim = 256;

    f32x16 acc;
#pragma unroll
    for (int r = 0; r < 16; ++r) acc[r] = 0.f;

    for (int kk = 0; kk < Kdim; kk += 32) {
        __syncthreads();
        {
            const float* Ap = A + (size_t)(m0 + ti) * Kdim + kk + seg * 8;
            float4 v0 = *reinterpret_cast<const float4*>(Ap);
            float4 v1 = *reinterpret_cast<const float4*>(Ap + 4);
            f16x4 lo = {(_Float16)v0.x, (_Float16)v0.y, (_Float16)v0.z, (_Float16)v0.w};
            f16x4 hi = {(_Float16)v1.x, (_Float16)v1.y, (_Float16)v1.z, (_Float16)v1.w};
            *reinterpret_cast<f16x4*>(&As[ti][seg * 8])     = lo;
            *reinterpret_cast<f16x4*>(&As[ti][seg * 8 + 4]) = hi;
        }
        {
            const float* Bp = B + (size_t)(n0 + ti) * Kdim + kk + seg * 8;
            float4 v0 = *reinterpret_cast<const float4*>(Bp);
            float4 v1 = *reinterpret_cast<const float4*>(Bp + 4);
            f16x4 lo = {(_Float16)v0.x, (_Float16)v0.y, (_Float16)v0.z, (_Float16)v0.w};
            f16x4 hi = {(_Float16)v1.x, (_Float16)v1.y, (_Float16)v1.z, (_Float16)v1.w};
            *reinterpret_cast<f16x4*>(&Bs[ti][seg * 8])     = lo;
            *reinterpret_cast<f16x4*>(&Bs[ti][seg * 8 + 4]) = hi;
        }
        __syncthreads();
#pragma unroll
        for (int kc = 0; kc < 4; ++kc) {
            f16x4 af = *reinterpret_cast<const f16x4*>(&As[wr + il][kc * 8 + 4 * g]);
            f16x4 bf = *reinterpret_cast<const f16x4*>(&Bs[wc + il][kc * 8 + 4 * g]);
            acc = mfma8f16(af, bf, acc);
        }
    }

    const int colg = n0 + wc + il;
    if (mode == 0) {
#pragma unroll
        for (int q = 0; q < 4; ++q) {
            const int row = m0 + wr + 8 * q + 4 * g;
            f16x4 v;
#pragma unroll
            for (int r = 0; r < 4; ++r) v[r] = (_Float16)acc[4 * q + r];
            *reinterpret_cast<f16x4*>(&outT[(size_t)colg * NN + row]) = v;
        }
    } else {
        const float bs = bias1[colg];
#pragma unroll
        for (int reg = 0; reg < 16; ++reg) {
            const int row = m0 + wr + (reg & 3) + 8 * (reg >> 2) + 4 * g;
            outF[(size_t)row * CALL + colg] = acc[reg] + bs;
        }
    }
}

// ---------------------------------------------------------------------------
// gemm2: final GEMM, A=hsum (f16), + bias + exact GELU
// ---------------------------------------------------------------------------
__global__ __launch_bounds__(256) void gemm2(
    const _Float16* __restrict__ A16, const float* __restrict__ B,
    const float* __restrict__ bias, float* __restrict__ outF)
{
    __shared__ _Float16 As[64][36];
    __shared__ _Float16 Bs[64][36];
    const int t = threadIdx.x;
    const int w = t >> 6, l = t & 63, g = l >> 5, il = l & 31;
    const int m0 = blockIdx.x * 64, n0 = blockIdx.y * 64;
    const int wr = (w >> 1) * 32, wc = (w & 1) * 32;
    const int ti = t >> 2, seg = t & 3;
    const int Kdim = 384;

    f32x16 acc;
#pragma unroll
    for (int r = 0; r < 16; ++r) acc[r] = 0.f;

    for (int kk = 0; kk < Kdim; kk += 32) {
        __syncthreads();
        {
            const uint4 v = *reinterpret_cast<const uint4*>(A16 + (size_t)(m0 + ti) * Kdim + kk + seg * 8);
            *reinterpret_cast<uint2*>(&As[ti][seg * 8])     = make_uint2(v.x, v.y);
            *reinterpret_cast<uint2*>(&As[ti][seg * 8 + 4]) = make_uint2(v.z, v.w);
        }
        {
            const float* Bp = B + (size_t)(n0 + ti) * Kdim + kk + seg * 8;
            float4 v0 = *reinterpret_cast<const float4*>(Bp);
            float4 v1 = *reinterpret_cast<const float4*>(Bp + 4);
            f16x4 lo = {(_Float16)v0.x, (_Float16)v0.y, (_Float16)v0.z, (_Float16)v0.w};
            f16x4 hi = {(_Float16)v1.x, (_Float16)v1.y, (_Float16)v1.z, (_Float16)v1.w};
            *reinterpret_cast<f16x4*>(&Bs[ti][seg * 8])     = lo;
            *reinterpret_cast<f16x4*>(&Bs[ti][seg * 8 + 4]) = hi;
        }
        __syncthreads();
#pragma unroll
        for (int kc = 0; kc < 4; ++kc) {
            f16x4 af = *reinterpret_cast<const f16x4*>(&As[wr + il][kc * 8 + 4 * g]);
            f16x4 bf = *reinterpret_cast<const f16x4*>(&Bs[wc + il][kc * 8 + 4 * g]);
            acc = mfma8f16(af, bf, acc);
        }
    }

    const int colg = n0 + wc + il;
    const float bs = bias[colg];
#pragma unroll
    for (int reg = 0; reg < 16; ++reg) {
        const int row = m0 + wr + (reg & 3) + 8 * (reg >> 2) + 4 * g;
        float vv = acc[reg] + bs;
        vv = 0.5f * vv * (1.0f + erff(vv * 0.70710678118f));
        outF[(size_t)row * CALL + colg] = vv;
    }
}

// ---------------------------------------------------------------------------
// a_src[n][h] (row-major) and a_dstT[h][n] (transposed, PRE-SCALED by log2e)
// ---------------------------------------------------------------------------
__global__ __launch_bounds__(256) void srcdst_kernel(
    const _Float16* __restrict__ hT, const float* __restrict__ attn_src,
    const float* __restrict__ attn_dst, float* __restrict__ asrc, float* __restrict__ adstT)
{
    __shared__ float ssrc[CALL], sdst[CALL];
    const int t = threadIdx.x;
    for (int idx = t; idx < CALL; idx += 256) { ssrc[idx] = attn_src[idx]; sdst[idx] = attn_dst[idx]; }
    __syncthreads();
    const int n = blockIdx.x * 64 + (t & 63);
    const int q = t >> 6;  // heads 3q..3q+2
#pragma unroll
    for (int hh = 0; hh < 3; ++hh) {
        float a0 = 0.f, a1 = 0.f;
        for (int dd = 0; dd < 32; ++dd) {
            const int c = q * 96 + hh * 32 + dd;
            const float v = (float)hT[(size_t)c * NN + n];
            a0 = fmaf(v, ssrc[c], a0);
            a1 = fmaf(v, sdst[c], a1);
        }
        asrc[n * NH + q * 3 + hh] = a0;
        adstT[(size_t)(q * 3 + hh) * NN + n] = a1 * 1.44269504089f;
    }
}

// ---------------------------------------------------------------------------
// attn4: block = 32-row band x 3 heads, 1024 threads = 16 waves (4/SIMD).
// Wave w owns j-chunk [w*128, w*128+128): 4 tiles of 32.
// Wave-private LDS: hT_s[96][36] f16 + adst_s[3][128] f32 (staged once).
// adj register-prefetched one tile ahead. No barriers in main loop.
// Epilogue: phased cross-wave reduce in a 4-wave red region (5 barriers).
// ---------------------------------------------------------------------------
__global__ __launch_bounds__(1024, 4) void attn4(
    const float* __restrict__ adj, const _Float16* __restrict__ hT,
    const float* __restrict__ asrc, const float* __restrict__ adstT,
    const float* __restrict__ eW, const float* __restrict__ eb,
    const float* __restrict__ res, _Float16* __restrict__ hsum)
{
    // per-wave slice at w*8448: hT_s[96][36] f16 (6912B) | adst_s[3*128] f32 (1536B)
    // epilogue overlay: red[4][3][16][64] f32 (49152B) at 0 | dsum_s[16][3][32] f32 (6144B) at 49152
    __shared__ __align__(16) char smem[135168];
    const int t = threadIdx.x;
    const int w = t >> 6, l = t & 63, g = l >> 5, il = l & 31;
    const int band = blockIdx.x & 63, hg = blockIdx.x >> 6;
    const int i0 = band * 32, h0 = hg * 3, c0 = hg * 96;

    _Float16 (*hT_s)[36] = (_Float16(*)[36])(smem + w * 8448);
    float* adst_s = (float*)(smem + w * 8448 + 6912);
    float* red    = (float*)smem;
    float* dsum_s = (float*)(smem + 49152);

    const float LOG2E = 1.44269504089f;
    float base_h[3], eWr[3];
#pragma unroll
    for (int hh = 0; hh < 3; ++hh) {
        base_h[hh] = (asrc[(size_t)(i0 + il) * NH + h0 + hh] + eb[h0 + hh]) * LOG2E;
        eWr[hh] = eW[h0 + hh] * LOG2E;
    }

    const int jbase = w * 128;
    // stage adst chunk for this wave's j-range (pre-scaled by log2e at producer)
#pragma unroll
    for (int p = 0; p < 6; ++p) {
        const int idx = p * 64 + l;
        adst_s[idx] = adstT[(size_t)(h0 + (idx >> 7)) * NN + jbase + (idx & 127)];
    }

    f32x16 acc[3];
#pragma unroll
    for (int hh = 0; hh < 3; ++hh)
#pragma unroll
        for (int r = 0; r < 16; ++r) acc[hh][r] = 0.f;
    float dsum[3] = {0.f, 0.f, 0.f};

    const float* adjrow = adj + (size_t)(i0 + il) * NN + jbase;
    float4 ajn[4];
#pragma unroll
    for (int p = 0; p < 4; ++p)
        ajn[p] = *reinterpret_cast<const float4*>(adjrow + p * 8 + 4 * g);

    for (int tl = 0; tl < 4; ++tl) {
        float4 ajc[4];
#pragma unroll
        for (int p = 0; p < 4; ++p) ajc[p] = ajn[p];
        // stage hT tile 96x32 (wave-private, no barrier)
        const int jb = jbase + tl * 32;
#pragma unroll
        for (int p = 0; p < 6; ++p) {
            const int r = p * 16 + (l >> 2), s = (l & 3) * 8;
            const uint4 v = *reinterpret_cast<const uint4*>(hT + (size_t)(c0 + r) * NN + jb + s);
            *reinterpret_cast<uint2*>(&hT_s[r][s])     = make_uint2(v.x, v.y);
            *reinterpret_cast<uint2*>(&hT_s[r][s + 4]) = make_uint2(v.z, v.w);
        }
        if (tl < 3) {
#pragma unroll
            for (int p = 0; p < 4; ++p)
                ajn[p] = *reinterpret_cast<const float4*>(adjrow + (tl + 1) * 32 + p * 8 + 4 * g);
        }

#pragma unroll
        for (int ks = 0; ks < 4; ++ks) {
            const float4 aj = ajc[ks];
#pragma unroll
            for (int hh = 0; hh < 3; ++hh) {
                const float4 ad = *reinterpret_cast<const float4*>(
                    &adst_s[hh * 128 + tl * 32 + ks * 8 + 4 * g]);
                f16x4 ef;
#pragma unroll
                for (int jj = 0; jj < 4; ++jj) {
                    const float ajv = (&aj.x)[jj];
                    float tt = fmaf(ajv, eWr[hh], base_h[hh] + (&ad.x)[jj]);
                    tt = fmaxf(tt, 0.2f * tt);
                    const float ee = ajv > 0.f ? exp2f(tt) : 0.f;
                    dsum[hh] += ee;
                    ef[jj] = (_Float16)ee;
                }
                const f16x4 vf = *reinterpret_cast<const f16x4*>(&hT_s[hh * 32 + il][ks * 8 + 4 * g]);
                acc[hh] = mfma8f16(ef, vf, acc[hh]);
            }
        }
    }

    // ---- epilogue: phased cross-wave reduce (16 waves -> 4-wave red region) ----
    __syncthreads();   // all waves done reading their staging slices
#pragma unroll
    for (int hh = 0; hh < 3; ++hh) {
        const float dtot = dsum[hh] + __shfl_xor(dsum[hh], 32);
        if (g == 0) dsum_s[(w * 3 + hh) * 32 + il] = dtot;
    }
    if (w < 4) {
#pragma unroll
        for (int hh = 0; hh < 3; ++hh)
#pragma unroll
            for (int reg = 0; reg < 16; ++reg)
                red[((w * 3 + hh) * 16 + reg) * 64 + l] = acc[hh][reg];
    }
    __syncthreads();
    if (w >= 4 && w < 8) {
#pragma unroll
        for (int hh = 0; hh < 3; ++hh)
#pragma unroll
            for (int reg = 0; reg < 16; ++reg)
                red[(((w - 4) * 3 + hh) * 16 + reg) * 64 + l] += acc[hh][reg];
    }
    __syncthreads();
    if (w >= 8 && w < 12) {
#pragma unroll
        for (int hh = 0; hh < 3; ++hh)
#pragma unroll
            for (int reg = 0; reg < 16; ++reg)
                red[(((w - 8) * 3 + hh) * 16 + reg) * 64 + l] += acc[hh][reg];
    }
    __syncthreads();
    if (w >= 12) {
#pragma unroll
        for (int hh = 0; hh < 3; ++hh)
#pragma unroll
            for (int reg = 0; reg < 16; ++reg)
                red[(((w - 12) * 3 + hh) * 16 + reg) * 64 + l] += acc[hh][reg];
    }
    __syncthreads();

    // output: wave w handles acc register index w (rows i0 + row_off)
    {
        const int reg = w;
        const int row_off = (reg & 3) + 8 * (reg >> 2) + 4 * g;
        const int row = i0 + row_off;
#pragma unroll
        for (int hh = 0; hh < 3; ++hh) {
            float v = 0.f, d = 0.f;
#pragma unroll
            for (int q = 0; q < 4; ++q)
                v += red[((q * 3 + hh) * 16 + reg) * 64 + l];
#pragma unroll
            for (int ww = 0; ww < 16; ++ww)
                d += dsum_s[(ww * 3 + hh) * 32 + row_off];
            const int col = (h0 + hh) * 32 + il;
            hsum[(size_t)row * CALL + col] = (_Float16)(v / d + res[(size_t)row * CALL + col]);
        }
    }
}

extern "C" void kernel_launch(void* const* d_in, const int* in_sizes, int n_in,
                              void* d_out, int out_size, void* d_ws, size_t ws_size,
                              hipStream_t stream)
{
    const float* x        = (const float*)d_in[0];
    const float* adj      = (const float*)d_in[1];
    const float* W        = (const float*)d_in[2];
    const float* attn_src = (const float*)d_in[3];
    const float* attn_dst = (const float*)d_in[4];
    const float* edge_W   = (const float*)d_in[5];
    const float* edge_b   = (const float*)d_in[6];
    const float* res_W    = (const float*)d_in[7];
    const float* res_b    = (const float*)d_in[8];
    const float* fus_W    = (const float*)d_in[9];
    const float* fus_b    = (const float*)d_in[10];
    float* out = (float*)d_out;

    char* ws = (char*)d_ws;
    size_t off = 0;
    auto alloc = [&](size_t bytes) { void* p = ws + off; off = (off + bytes + 255) & ~(size_t)255; return p; };
    _Float16* hT    = (_Float16*)alloc((size_t)CALL * NN * 2);
    float*    res   = (float*)alloc((size_t)NN * CALL * 4);
    float*    asrc  = (float*)alloc((size_t)NN * NH * 4);
    float*    adstT = (float*)alloc((size_t)NH * NN * 4);
    _Float16* hsum  = (_Float16*)alloc((size_t)NN * CALL * 2);
    (void)ws_size;

    gemm01<<<dim3(32, 6, 2), dim3(256), 0, stream>>>(x, W, res_W, res_b, hT, res);
    srcdst_kernel<<<32, dim3(256), 0, stream>>>(hT, attn_src, attn_dst, asrc, adstT);
    attn4<<<256, dim3(1024), 0, stream>>>(adj, hT, asrc, adstT, edge_W, edge_b, res, hsum);
    gemm2<<<dim3(32, 6), dim3(256), 0, stream>>>(hsum, fus_W, fus_b, out);
}

// Round 6
// 59.135 us; speedup vs baseline: 1.5537x; 1.0478x over previous
//
#include <hip/hip_runtime.h>
#include <hip/hip_bf16.h>

#define NN 2048
#define NH 12
#define HD 32
#define CALL 384   // NH*HD == OUT

typedef float f32x16 __attribute__((ext_vector_type(16)));
typedef _Float16 f16x4 __attribute__((ext_vector_type(4)));

static __device__ __forceinline__ f32x16 mfma8f16(f16x4 a, f16x4 b, f32x16 c) {
    return __builtin_amdgcn_mfma_f32_32x32x8f16(a, b, c, 0, 0, 0);
}
static __device__ __forceinline__ f16x4 u2f(uint2 u) {
    union { uint2 u2; f16x4 f; } c; c.u2 = u; return c.f;
}

// ---------------------------------------------------------------------------
// gemm01: fused first two GEMMs (share A = x, K=256).
// z=0: h = x W^T      -> outT (f16, transposed [384][2048])
// z=1: res = x resW^T -> outF (f32 [2048][384]) + bias
// ---------------------------------------------------------------------------
__global__ __launch_bounds__(256) void gemm01(
    const float* __restrict__ A, const float* __restrict__ B0,
    const float* __restrict__ B1, const float* __restrict__ bias1,
    _Float16* __restrict__ outT, float* __restrict__ outF)
{
    __shared__ _Float16 As[64][36];
    __shared__ _Float16 Bs[64][36];
    const int t = threadIdx.x;
    const int w = t >> 6, l = t & 63, g = l >> 5, il = l & 31;
    const int m0 = blockIdx.x * 64, n0 = blockIdx.y * 64;
    const int mode = blockIdx.z;
    const float* B = mode ? B1 : B0;
    const int wr = (w >> 1) * 32, wc = (w & 1) * 32;
    const int ti = t >> 2, seg = t & 3;
    const int Kdim = 256;

    f32x16 acc;
#pragma unroll
    for (int r = 0; r < 16; ++r) acc[r] = 0.f;

    for (int kk = 0; kk < Kdim; kk += 32) {
        __syncthreads();
        {
            const float* Ap = A + (size_t)(m0 + ti) * Kdim + kk + seg * 8;
            float4 v0 = *reinterpret_cast<const float4*>(Ap);
            float4 v1 = *reinterpret_cast<const float4*>(Ap + 4);
            f16x4 lo = {(_Float16)v0.x, (_Float16)v0.y, (_Float16)v0.z, (_Float16)v0.w};
            f16x4 hi = {(_Float16)v1.x, (_Float16)v1.y, (_Float16)v1.z, (_Float16)v1.w};
            *reinterpret_cast<f16x4*>(&As[ti][seg * 8])     = lo;
            *reinterpret_cast<f16x4*>(&As[ti][seg * 8 + 4]) = hi;
        }
        {
            const float* Bp = B + (size_t)(n0 + ti) * Kdim + kk + seg * 8;
            float4 v0 = *reinterpret_cast<const float4*>(Bp);
            float4 v1 = *reinterpret_cast<const float4*>(Bp + 4);
            f16x4 lo = {(_Float16)v0.x, (_Float16)v0.y, (_Float16)v0.z, (_Float16)v0.w};
            f16x4 hi = {(_Float16)v1.x, (_Float16)v1.y, (_Float16)v1.z, (_Float16)v1.w};
            *reinterpret_cast<f16x4*>(&Bs[ti][seg * 8])     = lo;
            *reinterpret_cast<f16x4*>(&Bs[ti][seg * 8 + 4]) = hi;
        }
        __syncthreads();
#pragma unroll
        for (int kc = 0; kc < 4; ++kc) {
            f16x4 af = *reinterpret_cast<const f16x4*>(&As[wr + il][kc * 8 + 4 * g]);
            f16x4 bf = *reinterpret_cast<const f16x4*>(&Bs[wc + il][kc * 8 + 4 * g]);
            acc = mfma8f16(af, bf, acc);
        }
    }

    const int colg = n0 + wc + il;
    if (mode == 0) {
#pragma unroll
        for (int q = 0; q < 4; ++q) {
            const int row = m0 + wr + 8 * q + 4 * g;
            f16x4 v;
#pragma unroll
            for (int r = 0; r < 4; ++r) v[r] = (_Float16)acc[4 * q + r];
            *reinterpret_cast<f16x4*>(&outT[(size_t)colg * NN + row]) = v;
        }
    } else {
        const float bs = bias1[colg];
#pragma unroll
        for (int reg = 0; reg < 16; ++reg) {
            const int row = m0 + wr + (reg & 3) + 8 * (reg >> 2) + 4 * g;
            outF[(size_t)row * CALL + colg] = acc[reg] + bs;
        }
    }
}

// ---------------------------------------------------------------------------
// gemm2: final GEMM, A=hsum (f16), + bias + exact GELU
// ---------------------------------------------------------------------------
__global__ __launch_bounds__(256) void gemm2(
    const _Float16* __restrict__ A16, const float* __restrict__ B,
    const float* __restrict__ bias, float* __restrict__ outF)
{
    __shared__ _Float16 As[64][36];
    __shared__ _Float16 Bs[64][36];
    const int t = threadIdx.x;
    const int w = t >> 6, l = t & 63, g = l >> 5, il = l & 31;
    const int m0 = blockIdx.x * 64, n0 = blockIdx.y * 64;
    const int wr = (w >> 1) * 32, wc = (w & 1) * 32;
    const int ti = t >> 2, seg = t & 3;
    const int Kdim = 384;

    f32x16 acc;
#pragma unroll
    for (int r = 0; r < 16; ++r) acc[r] = 0.f;

    for (int kk = 0; kk < Kdim; kk += 32) {
        __syncthreads();
        {
            const uint4 v = *reinterpret_cast<const uint4*>(A16 + (size_t)(m0 + ti) * Kdim + kk + seg * 8);
            *reinterpret_cast<uint2*>(&As[ti][seg * 8])     = make_uint2(v.x, v.y);
            *reinterpret_cast<uint2*>(&As[ti][seg * 8 + 4]) = make_uint2(v.z, v.w);
        }
        {
            const float* Bp = B + (size_t)(n0 + ti) * Kdim + kk + seg * 8;
            float4 v0 = *reinterpret_cast<const float4*>(Bp);
            float4 v1 = *reinterpret_cast<const float4*>(Bp + 4);
            f16x4 lo = {(_Float16)v0.x, (_Float16)v0.y, (_Float16)v0.z, (_Float16)v0.w};
            f16x4 hi = {(_Float16)v1.x, (_Float16)v1.y, (_Float16)v1.z, (_Float16)v1.w};
            *reinterpret_cast<f16x4*>(&Bs[ti][seg * 8])     = lo;
            *reinterpret_cast<f16x4*>(&Bs[ti][seg * 8 + 4]) = hi;
        }
        __syncthreads();
#pragma unroll
        for (int kc = 0; kc < 4; ++kc) {
            f16x4 af = *reinterpret_cast<const f16x4*>(&As[wr + il][kc * 8 + 4 * g]);
            f16x4 bf = *reinterpret_cast<const f16x4*>(&Bs[wc + il][kc * 8 + 4 * g]);
            acc = mfma8f16(af, bf, acc);
        }
    }

    const int colg = n0 + wc + il;
    const float bs = bias[colg];
#pragma unroll
    for (int reg = 0; reg < 16; ++reg) {
        const int row = m0 + wr + (reg & 3) + 8 * (reg >> 2) + 4 * g;
        float vv = acc[reg] + bs;
        vv = 0.5f * vv * (1.0f + erff(vv * 0.70710678118f));
        outF[(size_t)row * CALL + colg] = vv;
    }
}

// ---------------------------------------------------------------------------
// a_src[n][h] (row-major) and a_dstT[h][n] (transposed, PRE-SCALED by log2e)
// ---------------------------------------------------------------------------
__global__ __launch_bounds__(256) void srcdst_kernel(
    const _Float16* __restrict__ hT, const float* __restrict__ attn_src,
    const float* __restrict__ attn_dst, float* __restrict__ asrc, float* __restrict__ adstT)
{
    __shared__ float ssrc[CALL], sdst[CALL];
    const int t = threadIdx.x;
    for (int idx = t; idx < CALL; idx += 256) { ssrc[idx] = attn_src[idx]; sdst[idx] = attn_dst[idx]; }
    __syncthreads();
    const int n = blockIdx.x * 64 + (t & 63);
    const int q = t >> 6;  // heads 3q..3q+2
#pragma unroll
    for (int hh = 0; hh < 3; ++hh) {
        float a0 = 0.f, a1 = 0.f;
        for (int dd = 0; dd < 32; ++dd) {
            const int c = q * 96 + hh * 32 + dd;
            const float v = (float)hT[(size_t)c * NN + n];
            a0 = fmaf(v, ssrc[c], a0);
            a1 = fmaf(v, sdst[c], a1);
        }
        asrc[n * NH + q * 3 + hh] = a0;
        adstT[(size_t)(q * 3 + hh) * NN + n] = a1 * 1.44269504089f;
    }
}

// ---------------------------------------------------------------------------
// attn5: block = 32-row band x 3 heads, 1024 threads = 16 waves (4/SIMD).
// Wave w owns j-chunk [w*128, w*128+128): 4 tiles of 32.
// NO hT/adj LDS staging: intra-tile k<->j bijection j = 16g + 4ks + jj makes
// each lane's 4 B-fragments 32 CONTIGUOUS bytes of one hT row -> 2x dwordx4
// straight to regs (zero cross-lane reuse existed, LDS was pure overhead).
// adj likewise 64B contiguous per lane. Only adst (reused) stays in LDS.
// No barriers in the main loop -> compiler hoists next-tile loads freely.
// Epilogue: phased cross-wave reduce in a 4-wave red region (5 barriers).
// ---------------------------------------------------------------------------
__global__ __launch_bounds__(1024, 4) void attn5(
    const float* __restrict__ adj, const _Float16* __restrict__ hT,
    const float* __restrict__ asrc, const float* __restrict__ adstT,
    const float* __restrict__ eW, const float* __restrict__ eb,
    const float* __restrict__ res, _Float16* __restrict__ hsum)
{
    // staging: per-wave adst_s[3*128] f32 at w*1536 (24KB total)
    // epilogue overlay: red[4][3][16][64] f32 (49152B) at 0 | dsum_s[16][3][32] f32 (6144B) at 49152
    __shared__ __align__(16) char smem[55296];
    const int t = threadIdx.x;
    const int w = t >> 6, l = t & 63, g = l >> 5, il = l & 31;
    const int band = blockIdx.x & 63, hg = blockIdx.x >> 6;
    const int i0 = band * 32, h0 = hg * 3, c0 = hg * 96;

    float* adst_s = (float*)(smem + w * 1536);
    float* red    = (float*)smem;
    float* dsum_s = (float*)(smem + 49152);

    const float LOG2E = 1.44269504089f;
    float base_h[3], eWr[3];
#pragma unroll
    for (int hh = 0; hh < 3; ++hh) {
        base_h[hh] = (asrc[(size_t)(i0 + il) * NH + h0 + hh] + eb[h0 + hh]) * LOG2E;
        eWr[hh] = eW[h0 + hh] * LOG2E;
    }

    const int jbase = w * 128;
    // stage adst chunk for this wave's j-range (pre-scaled by log2e at producer)
#pragma unroll
    for (int p = 0; p < 6; ++p) {
        const int idx = p * 64 + l;
        adst_s[idx] = adstT[(size_t)(h0 + (idx >> 7)) * NN + jbase + (idx & 127)];
    }

    f32x16 acc[3];
#pragma unroll
    for (int hh = 0; hh < 3; ++hh)
#pragma unroll
        for (int r = 0; r < 16; ++r) acc[hh][r] = 0.f;
    float dsum[3] = {0.f, 0.f, 0.f};

    const _Float16* hbase = hT  + (size_t)(c0 + il) * NN + jbase + 16 * g;
    const float*    abase = adj + (size_t)(i0 + il) * NN + jbase + 16 * g;

#pragma unroll 2
    for (int tl = 0; tl < 4; ++tl) {
        const int jo = tl * 32;
        // hT B-fragments: 32B contiguous per (head, lane)
        uint4 hA[3], hB[3];
#pragma unroll
        for (int hh = 0; hh < 3; ++hh) {
            const _Float16* hp = hbase + (size_t)(hh * 32) * NN + jo;
            hA[hh] = *reinterpret_cast<const uint4*>(hp);
            hB[hh] = *reinterpret_cast<const uint4*>(hp + 8);
        }
        // adj: 64B contiguous per lane
        float4 aj[4];
#pragma unroll
        for (int p = 0; p < 4; ++p)
            aj[p] = *reinterpret_cast<const float4*>(abase + jo + 4 * p);

#pragma unroll
        for (int ks = 0; ks < 4; ++ks) {
            const float4 a4 = aj[ks];
#pragma unroll
            for (int hh = 0; hh < 3; ++hh) {
                const float4 ad = *reinterpret_cast<const float4*>(
                    &adst_s[hh * 128 + jo + 16 * g + 4 * ks]);
                f16x4 ef;
#pragma unroll
                for (int jj = 0; jj < 4; ++jj) {
                    const float ajv = (&a4.x)[jj];
                    float tt = fmaf(ajv, eWr[hh], base_h[hh] + (&ad.x)[jj]);
                    tt = fmaxf(tt, 0.2f * tt);
                    const float ee = ajv > 0.f ? exp2f(tt) : 0.f;
                    dsum[hh] += ee;
                    ef[jj] = (_Float16)ee;
                }
                const uint2 hu = (ks == 0) ? make_uint2(hA[hh].x, hA[hh].y)
                               : (ks == 1) ? make_uint2(hA[hh].z, hA[hh].w)
                               : (ks == 2) ? make_uint2(hB[hh].x, hB[hh].y)
                                           : make_uint2(hB[hh].z, hB[hh].w);
                acc[hh] = mfma8f16(ef, u2f(hu), acc[hh]);
            }
        }
    }

    // ---- epilogue: phased cross-wave reduce (16 waves -> 4-wave red region) ----
    __syncthreads();   // all waves done reading adst_s
#pragma unroll
    for (int hh = 0; hh < 3; ++hh) {
        const float dtot = dsum[hh] + __shfl_xor(dsum[hh], 32);
        if (g == 0) dsum_s[(w * 3 + hh) * 32 + il] = dtot;
    }
    if (w < 4) {
#pragma unroll
        for (int hh = 0; hh < 3; ++hh)
#pragma unroll
            for (int reg = 0; reg < 16; ++reg)
                red[((w * 3 + hh) * 16 + reg) * 64 + l] = acc[hh][reg];
    }
    __syncthreads();
    if (w >= 4 && w < 8) {
#pragma unroll
        for (int hh = 0; hh < 3; ++hh)
#pragma unroll
            for (int reg = 0; reg < 16; ++reg)
                red[(((w - 4) * 3 + hh) * 16 + reg) * 64 + l] += acc[hh][reg];
    }
    __syncthreads();
    if (w >= 8 && w < 12) {
#pragma unroll
        for (int hh = 0; hh < 3; ++hh)
#pragma unroll
            for (int reg = 0; reg < 16; ++reg)
                red[(((w - 8) * 3 + hh) * 16 + reg) * 64 + l] += acc[hh][reg];
    }
    __syncthreads();
    if (w >= 12) {
#pragma unroll
        for (int hh = 0; hh < 3; ++hh)
#pragma unroll
            for (int reg = 0; reg < 16; ++reg)
                red[(((w - 12) * 3 + hh) * 16 + reg) * 64 + l] += acc[hh][reg];
    }
    __syncthreads();

    // output: wave w handles acc register index w (rows i0 + row_off)
    {
        const int reg = w;
        const int row_off = (reg & 3) + 8 * (reg >> 2) + 4 * g;
        const int row = i0 + row_off;
#pragma unroll
        for (int hh = 0; hh < 3; ++hh) {
            float v = 0.f, d = 0.f;
#pragma unroll
            for (int q = 0; q < 4; ++q)
                v += red[((q * 3 + hh) * 16 + reg) * 64 + l];
#pragma unroll
            for (int ww = 0; ww < 16; ++ww)
                d += dsum_s[(ww * 3 + hh) * 32 + row_off];
            const int col = (h0 + hh) * 32 + il;
            hsum[(size_t)row * CALL + col] = (_Float16)(v / d + res[(size_t)row * CALL + col]);
        }
    }
}

extern "C" void kernel_launch(void* const* d_in, const int* in_sizes, int n_in,
                              void* d_out, int out_size, void* d_ws, size_t ws_size,
                              hipStream_t stream)
{
    const float* x        = (const float*)d_in[0];
    const float* adj      = (const float*)d_in[1];
    const float* W        = (const float*)d_in[2];
    const float* attn_src = (const float*)d_in[3];
    const float* attn_dst = (const float*)d_in[4];
    const float* edge_W   = (const float*)d_in[5];
    const float* edge_b   = (const float*)d_in[6];
    const float* res_W    = (const float*)d_in[7];
    const float* res_b    = (const float*)d_in[8];
    const float* fus_W    = (const float*)d_in[9];
    const float* fus_b    = (const float*)d_in[10];
    float* out = (float*)d_out;

    char* ws = (char*)d_ws;
    size_t off = 0;
    auto alloc = [&](size_t bytes) { void* p = ws + off; off = (off + bytes + 255) & ~(size_t)255; return p; };
    _Float16* hT    = (_Float16*)alloc((size_t)CALL * NN * 2);
    float*    res   = (float*)alloc((size_t)NN * CALL * 4);
    float*    asrc  = (float*)alloc((size_t)NN * NH * 4);
    float*    adstT = (float*)alloc((size_t)NH * NN * 4);
    _Float16* hsum  = (_Float16*)alloc((size_t)NN * CALL * 2);
    (void)ws_size;

    gemm01<<<dim3(32, 6, 2), dim3(256), 0, stream>>>(x, W, res_W, res_b, hT, res);
    srcdst_kernel<<<32, dim3(256), 0, stream>>>(hT, attn_src, attn_dst, asrc, adstT);
    attn5<<<256, dim3(1024), 0, stream>>>(adj, hT, asrc, adstT, edge_W, edge_b, res, hsum);
    gemm2<<<dim3(32, 6), dim3(256), 0, stream>>>(hsum, fus_W, fus_b, out);
}

// Round 7
// 56.158 us; speedup vs baseline: 1.6361x; 1.0530x over previous
//
#include <hip/hip_runtime.h>
#include <hip/hip_bf16.h>

#define NN 2048
#define NH 12
#define HD 32
#define CALL 384   // NH*HD == OUT

typedef float f32x16 __attribute__((ext_vector_type(16)));
typedef _Float16 f16x4 __attribute__((ext_vector_type(4)));

static __device__ __forceinline__ f32x16 mfma8f16(f16x4 a, f16x4 b, f32x16 c) {
    return __builtin_amdgcn_mfma_f32_32x32x8f16(a, b, c, 0, 0, 0);
}
static __device__ __forceinline__ f16x4 u2f(uint2 u) {
    union { uint2 u2; f16x4 f; } c; c.u2 = u; return c.f;
}

// ---------------------------------------------------------------------------
// gemm01: fused first two GEMMs (share A = x, K=256).
// z=0: h = x W^T -> outT (f16, transposed [384][2048])  + FUSED srcdst:
//      each wave holds a complete (32 rows x 1 head) tile -> cross-lane
//      shfl_xor reduction gives a_src[n][h] and a_dstT[h][n] (pre-scaled
//      by log2e) with no extra kernel and no hT re-read.
// z=1: res = x resW^T -> outF (f32 [2048][384]) + bias
// ---------------------------------------------------------------------------
__global__ __launch_bounds__(256) void gemm01(
    const float* __restrict__ A, const float* __restrict__ B0,
    const float* __restrict__ B1, const float* __restrict__ bias1,
    const float* __restrict__ attn_src, const float* __restrict__ attn_dst,
    _Float16* __restrict__ outT, float* __restrict__ outF,
    float* __restrict__ asrc, float* __restrict__ adstT)
{
    __shared__ _Float16 As[64][36];
    __shared__ _Float16 Bs[64][36];
    const int t = threadIdx.x;
    const int w = t >> 6, l = t & 63, g = l >> 5, il = l & 31;
    const int m0 = blockIdx.x * 64, n0 = blockIdx.y * 64;
    const int mode = blockIdx.z;
    const float* B = mode ? B1 : B0;
    const int wr = (w >> 1) * 32, wc = (w & 1) * 32;
    const int ti = t >> 2, seg = t & 3;
    const int Kdim = 256;

    f32x16 acc;
#pragma unroll
    for (int r = 0; r < 16; ++r) acc[r] = 0.f;

    for (int kk = 0; kk < Kdim; kk += 32) {
        __syncthreads();
        {
            const float* Ap = A + (size_t)(m0 + ti) * Kdim + kk + seg * 8;
            float4 v0 = *reinterpret_cast<const float4*>(Ap);
            float4 v1 = *reinterpret_cast<const float4*>(Ap + 4);
            f16x4 lo = {(_Float16)v0.x, (_Float16)v0.y, (_Float16)v0.z, (_Float16)v0.w};
            f16x4 hi = {(_Float16)v1.x, (_Float16)v1.y, (_Float16)v1.z, (_Float16)v1.w};
            *reinterpret_cast<f16x4*>(&As[ti][seg * 8])     = lo;
            *reinterpret_cast<f16x4*>(&As[ti][seg * 8 + 4]) = hi;
        }
        {
            const float* Bp = B + (size_t)(n0 + ti) * Kdim + kk + seg * 8;
            float4 v0 = *reinterpret_cast<const float4*>(Bp);
            float4 v1 = *reinterpret_cast<const float4*>(Bp + 4);
            f16x4 lo = {(_Float16)v0.x, (_Float16)v0.y, (_Float16)v0.z, (_Float16)v0.w};
            f16x4 hi = {(_Float16)v1.x, (_Float16)v1.y, (_Float16)v1.z, (_Float16)v1.w};
            *reinterpret_cast<f16x4*>(&Bs[ti][seg * 8])     = lo;
            *reinterpret_cast<f16x4*>(&Bs[ti][seg * 8 + 4]) = hi;
        }
        __syncthreads();
#pragma unroll
        for (int kc = 0; kc < 4; ++kc) {
            f16x4 af = *reinterpret_cast<const f16x4*>(&As[wr + il][kc * 8 + 4 * g]);
            f16x4 bf = *reinterpret_cast<const f16x4*>(&Bs[wc + il][kc * 8 + 4 * g]);
            acc = mfma8f16(af, bf, acc);
        }
    }

    const int colg = n0 + wc + il;
    if (mode == 0) {
#pragma unroll
        for (int q = 0; q < 4; ++q) {
            const int row = m0 + wr + 8 * q + 4 * g;
            f16x4 v;
#pragma unroll
            for (int r = 0; r < 4; ++r) v[r] = (_Float16)acc[4 * q + r];
            *reinterpret_cast<f16x4*>(&outT[(size_t)colg * NN + row]) = v;
        }
        // ---- fused srcdst: wave covers head hstar fully (cols = 32 d's) ----
        const int hstar = colg >> 5;                 // (n0+wc)/32
        const float sv = attn_src[hstar * HD + il];
        const float dv = attn_dst[hstar * HD + il];
        float ps[16], pd[16];
#pragma unroll
        for (int r = 0; r < 16; ++r) { ps[r] = acc[r] * sv; pd[r] = acc[r] * dv; }
#pragma unroll
        for (int m = 1; m <= 16; m <<= 1) {
#pragma unroll
            for (int r = 0; r < 16; ++r) {
                ps[r] += __shfl_xor(ps[r], m);
                pd[r] += __shfl_xor(pd[r], m);
            }
        }
        if (il == 0) {
#pragma unroll
            for (int r = 0; r < 16; ++r) {
                const int row = m0 + wr + (r & 3) + 8 * (r >> 2) + 4 * g;
                asrc[row * NH + hstar] = ps[r];
                adstT[(size_t)hstar * NN + row] = pd[r] * 1.44269504089f;
            }
        }
    } else {
        const float bs = bias1[colg];
#pragma unroll
        for (int reg = 0; reg < 16; ++reg) {
            const int row = m0 + wr + (reg & 3) + 8 * (reg >> 2) + 4 * g;
            outF[(size_t)row * CALL + colg] = acc[reg] + bs;
        }
    }
}

// ---------------------------------------------------------------------------
// gemm2: final GEMM, A=hsum (f16), + bias + exact GELU
// ---------------------------------------------------------------------------
__global__ __launch_bounds__(256) void gemm2(
    const _Float16* __restrict__ A16, const float* __restrict__ B,
    const float* __restrict__ bias, float* __restrict__ outF)
{
    __shared__ _Float16 As[64][36];
    __shared__ _Float16 Bs[64][36];
    const int t = threadIdx.x;
    const int w = t >> 6, l = t & 63, g = l >> 5, il = l & 31;
    const int m0 = blockIdx.x * 64, n0 = blockIdx.y * 64;
    const int wr = (w >> 1) * 32, wc = (w & 1) * 32;
    const int ti = t >> 2, seg = t & 3;
    const int Kdim = 384;

    f32x16 acc;
#pragma unroll
    for (int r = 0; r < 16; ++r) acc[r] = 0.f;

    for (int kk = 0; kk < Kdim; kk += 32) {
        __syncthreads();
        {
            const uint4 v = *reinterpret_cast<const uint4*>(A16 + (size_t)(m0 + ti) * Kdim + kk + seg * 8);
            *reinterpret_cast<uint2*>(&As[ti][seg * 8])     = make_uint2(v.x, v.y);
            *reinterpret_cast<uint2*>(&As[ti][seg * 8 + 4]) = make_uint2(v.z, v.w);
        }
        {
            const float* Bp = B + (size_t)(n0 + ti) * Kdim + kk + seg * 8;
            float4 v0 = *reinterpret_cast<const float4*>(Bp);
            float4 v1 = *reinterpret_cast<const float4*>(Bp + 4);
            f16x4 lo = {(_Float16)v0.x, (_Float16)v0.y, (_Float16)v0.z, (_Float16)v0.w};
            f16x4 hi = {(_Float16)v1.x, (_Float16)v1.y, (_Float16)v1.z, (_Float16)v1.w};
            *reinterpret_cast<f16x4*>(&Bs[ti][seg * 8])     = lo;
            *reinterpret_cast<f16x4*>(&Bs[ti][seg * 8 + 4]) = hi;
        }
        __syncthreads();
#pragma unroll
        for (int kc = 0; kc < 4; ++kc) {
            f16x4 af = *reinterpret_cast<const f16x4*>(&As[wr + il][kc * 8 + 4 * g]);
            f16x4 bf = *reinterpret_cast<const f16x4*>(&Bs[wc + il][kc * 8 + 4 * g]);
            acc = mfma8f16(af, bf, acc);
        }
    }

    const int colg = n0 + wc + il;
    const float bs = bias[colg];
#pragma unroll
    for (int reg = 0; reg < 16; ++reg) {
        const int row = m0 + wr + (reg & 3) + 8 * (reg >> 2) + 4 * g;
        float vv = acc[reg] + bs;
        vv = 0.5f * vv * (1.0f + erff(vv * 0.70710678118f));
        outF[(size_t)row * CALL + colg] = vv;
    }
}

// ---------------------------------------------------------------------------
// attn6: block = 32-row band x 3 heads, 1024 threads = 16 waves (4/SIMD).
// Wave w owns j-chunk [w*128, w*128+128): 4 tiles of 32.
// Register-pressure-conscious: hT fragments loaded inside the hh loop
// (8 live regs, L2-resident), only adj (the HBM stream) double-buffered
// across tiles. adst in wave-private LDS. No barriers in the main loop.
// Epilogue: phased cross-wave reduce in a 4-wave red region (5 barriers).
// ---------------------------------------------------------------------------
__global__ __launch_bounds__(1024, 4) void attn6(
    const float* __restrict__ adj, const _Float16* __restrict__ hT,
    const float* __restrict__ asrc, const float* __restrict__ adstT,
    const float* __restrict__ eW, const float* __restrict__ eb,
    const float* __restrict__ res, _Float16* __restrict__ hsum)
{
    // staging: per-wave adst_s[3*128] f32 at w*1536 (24KB total)
    // epilogue overlay: red[4][3][16][64] f32 (49152B) at 0 | dsum_s[16][3][32] f32 (6144B) at 49152
    __shared__ __align__(16) char smem[55296];
    const int t = threadIdx.x;
    const int w = t >> 6, l = t & 63, g = l >> 5, il = l & 31;
    const int band = blockIdx.x & 63, hg = blockIdx.x >> 6;
    const int i0 = band * 32, h0 = hg * 3, c0 = hg * 96;

    float* adst_s = (float*)(smem + w * 1536);
    float* red    = (float*)smem;
    float* dsum_s = (float*)(smem + 49152);

    const float LOG2E = 1.44269504089f;
    float base_h[3], eWr[3];
#pragma unroll
    for (int hh = 0; hh < 3; ++hh) {
        base_h[hh] = (asrc[(size_t)(i0 + il) * NH + h0 + hh] + eb[h0 + hh]) * LOG2E;
        eWr[hh] = eW[h0 + hh] * LOG2E;
    }

    const int jbase = w * 128;
    // stage adst chunk for this wave's j-range (pre-scaled by log2e at producer)
#pragma unroll
    for (int p = 0; p < 6; ++p) {
        const int idx = p * 64 + l;
        adst_s[idx] = adstT[(size_t)(h0 + (idx >> 7)) * NN + jbase + (idx & 127)];
    }

    f32x16 acc[3];
#pragma unroll
    for (int hh = 0; hh < 3; ++hh)
#pragma unroll
        for (int r = 0; r < 16; ++r) acc[hh][r] = 0.f;
    float dsum[3] = {0.f, 0.f, 0.f};

    const _Float16* hbase = hT  + (size_t)(c0 + il) * NN + jbase + 16 * g;
    const float*    abase = adj + (size_t)(i0 + il) * NN + jbase + 16 * g;

    // adj: double-buffered across tiles (HBM-latency stream)
    float4 ajc[4], ajn[4];
#pragma unroll
    for (int p = 0; p < 4; ++p)
        ajc[p] = *reinterpret_cast<const float4*>(abase + 4 * p);

#pragma unroll 1
    for (int tl = 0; tl < 4; ++tl) {
        const int jo = tl * 32;
        if (tl < 3) {
#pragma unroll
            for (int p = 0; p < 4; ++p)
                ajn[p] = *reinterpret_cast<const float4*>(abase + jo + 32 + 4 * p);
        }
#pragma unroll
        for (int hh = 0; hh < 3; ++hh) {
            const _Float16* hp = hbase + (size_t)(hh * 32) * NN + jo;
            const uint4 hA = *reinterpret_cast<const uint4*>(hp);      // j [16g, 16g+8)
            const uint4 hB = *reinterpret_cast<const uint4*>(hp + 8);  // j [16g+8, 16g+16)
#pragma unroll
            for (int ks = 0; ks < 4; ++ks) {
                const float4 a4 = ajc[ks];
                const float4 ad = *reinterpret_cast<const float4*>(
                    &adst_s[hh * 128 + jo + 16 * g + 4 * ks]);
                f16x4 ef;
#pragma unroll
                for (int jj = 0; jj < 4; ++jj) {
                    const float ajv = (&a4.x)[jj];
                    float tt = fmaf(ajv, eWr[hh], base_h[hh] + (&ad.x)[jj]);
                    tt = fmaxf(tt, 0.2f * tt);
                    const float ee = ajv > 0.f ? exp2f(tt) : 0.f;
                    dsum[hh] += ee;
                    ef[jj] = (_Float16)ee;
                }
                const uint2 hu = (ks == 0) ? make_uint2(hA.x, hA.y)
                               : (ks == 1) ? make_uint2(hA.z, hA.w)
                               : (ks == 2) ? make_uint2(hB.x, hB.y)
                                           : make_uint2(hB.z, hB.w);
                acc[hh] = mfma8f16(ef, u2f(hu), acc[hh]);
            }
        }
#pragma unroll
        for (int p = 0; p < 4; ++p) ajc[p] = ajn[p];
    }

    // ---- epilogue: phased cross-wave reduce (16 waves -> 4-wave red region) ----
    __syncthreads();   // all waves done reading adst_s
#pragma unroll
    for (int hh = 0; hh < 3; ++hh) {
        const float dtot = dsum[hh] + __shfl_xor(dsum[hh], 32);
        if (g == 0) dsum_s[(w * 3 + hh) * 32 + il] = dtot;
    }
    if (w < 4) {
#pragma unroll
        for (int hh = 0; hh < 3; ++hh)
#pragma unroll
            for (int reg = 0; reg < 16; ++reg)
                red[((w * 3 + hh) * 16 + reg) * 64 + l] = acc[hh][reg];
    }
    __syncthreads();
    if (w >= 4 && w < 8) {
#pragma unroll
        for (int hh = 0; hh < 3; ++hh)
#pragma unroll
            for (int reg = 0; reg < 16; ++reg)
                red[(((w - 4) * 3 + hh) * 16 + reg) * 64 + l] += acc[hh][reg];
    }
    __syncthreads();
    if (w >= 8 && w < 12) {
#pragma unroll
        for (int hh = 0; hh < 3; ++hh)
#pragma unroll
            for (int reg = 0; reg < 16; ++reg)
                red[(((w - 8) * 3 + hh) * 16 + reg) * 64 + l] += acc[hh][reg];
    }
    __syncthreads();
    if (w >= 12) {
#pragma unroll
        for (int hh = 0; hh < 3; ++hh)
#pragma unroll
            for (int reg = 0; reg < 16; ++reg)
                red[(((w - 12) * 3 + hh) * 16 + reg) * 64 + l] += acc[hh][reg];
    }
    __syncthreads();

    // output: wave w handles acc register index w (rows i0 + row_off)
    {
        const int reg = w;
        const int row_off = (reg & 3) + 8 * (reg >> 2) + 4 * g;
        const int row = i0 + row_off;
#pragma unroll
        for (int hh = 0; hh < 3; ++hh) {
            float v = 0.f, d = 0.f;
#pragma unroll
            for (int q = 0; q < 4; ++q)
                v += red[((q * 3 + hh) * 16 + reg) * 64 + l];
#pragma unroll
            for (int ww = 0; ww < 16; ++ww)
                d += dsum_s[(ww * 3 + hh) * 32 + row_off];
            const int col = (h0 + hh) * 32 + il;
            hsum[(size_t)row * CALL + col] = (_Float16)(v / d + res[(size_t)row * CALL + col]);
        }
    }
}

extern "C" void kernel_launch(void* const* d_in, const int* in_sizes, int n_in,
                              void* d_out, int out_size, void* d_ws, size_t ws_size,
                              hipStream_t stream)
{
    const float* x        = (const float*)d_in[0];
    const float* adj      = (const float*)d_in[1];
    const float* W        = (const float*)d_in[2];
    const float* attn_src = (const float*)d_in[3];
    const float* attn_dst = (const float*)d_in[4];
    const float* edge_W   = (const float*)d_in[5];
    const float* edge_b   = (const float*)d_in[6];
    const float* res_W    = (const float*)d_in[7];
    const float* res_b    = (const float*)d_in[8];
    const float* fus_W    = (const float*)d_in[9];
    const float* fus_b    = (const float*)d_in[10];
    float* out = (float*)d_out;

    char* ws = (char*)d_ws;
    size_t off = 0;
    auto alloc = [&](size_t bytes) { void* p = ws + off; off = (off + bytes + 255) & ~(size_t)255; return p; };
    _Float16* hT    = (_Float16*)alloc((size_t)CALL * NN * 2);
    float*    res   = (float*)alloc((size_t)NN * CALL * 4);
    float*    asrc  = (float*)alloc((size_t)NN * NH * 4);
    float*    adstT = (float*)alloc((size_t)NH * NN * 4);
    _Float16* hsum  = (_Float16*)alloc((size_t)NN * CALL * 2);
    (void)ws_size;

    gemm01<<<dim3(32, 6, 2), dim3(256), 0, stream>>>(x, W, res_W, res_b, attn_src, attn_dst, hT, res, asrc, adstT);
    attn6<<<256, dim3(1024), 0, stream>>>(adj, hT, asrc, adstT, edge_W, edge_b, res, hsum);
    gemm2<<<dim3(32, 6), dim3(256), 0, stream>>>(hsum, fus_W, fus_b, out);
}

// Round 8
// 52.536 us; speedup vs baseline: 1.7489x; 1.0689x over previous
//
#include <hip/hip_runtime.h>
#include <hip/hip_bf16.h>

#define NN 2048
#define NH 12
#define HD 32
#define CALL 384   // NH*HD == OUT

typedef float f32x16 __attribute__((ext_vector_type(16)));
typedef _Float16 f16x4 __attribute__((ext_vector_type(4)));

static __device__ __forceinline__ f32x16 mfma8f16(f16x4 a, f16x4 b, f32x16 c) {
    return __builtin_amdgcn_mfma_f32_32x32x8f16(a, b, c, 0, 0, 0);
}
static __device__ __forceinline__ f16x4 u2f(uint2 u) {
    union { uint2 u2; f16x4 f; } c; c.u2 = u; return c.f;
}

// ---------------------------------------------------------------------------
// gemm01: fused first two GEMMs (share A = x, K=256), K-SPLIT 8-wave blocks.
// 512 thr = 8 waves: quadrant q = w&3 (2x2 of 32x32), k-group kg = w>>2.
// Superstep stages a 64-row x 64-k tile of A and B once; kg0 consumes
// k[0,32), kg1 k[32,64) concurrently -> 4 supersteps instead of 8 k-steps.
// Merge kg1 partials into kg0 via 16KB LDS overlay (2 barriers, end only).
// z=0: h = x W^T -> outT (f16, transposed [384][2048]) + FUSED srcdst
// z=1: res = x resW^T -> outF (f32 [2048][384]) + bias
// ---------------------------------------------------------------------------
__global__ __launch_bounds__(512) void gemm01(
    const float* __restrict__ A, const float* __restrict__ B0,
    const float* __restrict__ B1, const float* __restrict__ bias1,
    const float* __restrict__ attn_src, const float* __restrict__ attn_dst,
    _Float16* __restrict__ outT, float* __restrict__ outF,
    float* __restrict__ asrc, float* __restrict__ adstT)
{
    __shared__ __align__(16) char smem[17408];   // As 8704 | Bs 8704 ; red 16KB overlays
    _Float16 (*As)[68] = (_Float16(*)[68])(smem);
    _Float16 (*Bs)[68] = (_Float16(*)[68])(smem + 8704);
    float* red = (float*)smem;

    const int t = threadIdx.x;
    const int w = t >> 6, l = t & 63, g = l >> 5, il = l & 31;
    const int q = w & 3, kg = w >> 2;
    const int m0 = blockIdx.x * 64, n0 = blockIdx.y * 64;
    const int mode = blockIdx.z;
    const float* B = mode ? B1 : B0;
    const int wr = (q >> 1) * 32, wc = (q & 1) * 32;
    const int ti = t >> 3, seg = t & 7;          // staging: row 0..63, 8-col segment
    const int Kdim = 256;

    f32x16 acc;
#pragma unroll
    for (int r = 0; r < 16; ++r) acc[r] = 0.f;

#pragma unroll 1
    for (int ss = 0; ss < 4; ++ss) {
        const int kk = ss * 64;
        __syncthreads();
        {
            const float* Ap = A + (size_t)(m0 + ti) * Kdim + kk + seg * 8;
            float4 v0 = *reinterpret_cast<const float4*>(Ap);
            float4 v1 = *reinterpret_cast<const float4*>(Ap + 4);
            f16x4 lo = {(_Float16)v0.x, (_Float16)v0.y, (_Float16)v0.z, (_Float16)v0.w};
            f16x4 hi = {(_Float16)v1.x, (_Float16)v1.y, (_Float16)v1.z, (_Float16)v1.w};
            *reinterpret_cast<f16x4*>(&As[ti][seg * 8])     = lo;
            *reinterpret_cast<f16x4*>(&As[ti][seg * 8 + 4]) = hi;
        }
        {
            const float* Bp = B + (size_t)(n0 + ti) * Kdim + kk + seg * 8;
            float4 v0 = *reinterpret_cast<const float4*>(Bp);
            float4 v1 = *reinterpret_cast<const float4*>(Bp + 4);
            f16x4 lo = {(_Float16)v0.x, (_Float16)v0.y, (_Float16)v0.z, (_Float16)v0.w};
            f16x4 hi = {(_Float16)v1.x, (_Float16)v1.y, (_Float16)v1.z, (_Float16)v1.w};
            *reinterpret_cast<f16x4*>(&Bs[ti][seg * 8])     = lo;
            *reinterpret_cast<f16x4*>(&Bs[ti][seg * 8 + 4]) = hi;
        }
        __syncthreads();
#pragma unroll
        for (int kc = 0; kc < 4; ++kc) {
            f16x4 af = *reinterpret_cast<const f16x4*>(&As[wr + il][kg * 32 + kc * 8 + 4 * g]);
            f16x4 bf = *reinterpret_cast<const f16x4*>(&Bs[wc + il][kg * 32 + kc * 8 + 4 * g]);
            acc = mfma8f16(af, bf, acc);
        }
    }

    // merge kg1 -> kg0 through LDS overlay
    __syncthreads();
    if (kg == 1) {
#pragma unroll
        for (int r = 0; r < 16; ++r) red[(q * 16 + r) * 64 + l] = acc[r];
    }
    __syncthreads();
    if (kg != 0) return;
#pragma unroll
    for (int r = 0; r < 16; ++r) acc[r] += red[(q * 16 + r) * 64 + l];

    const int colg = n0 + wc + il;
    if (mode == 0) {
#pragma unroll
        for (int p = 0; p < 4; ++p) {
            const int row = m0 + wr + 8 * p + 4 * g;
            f16x4 v;
#pragma unroll
            for (int r = 0; r < 4; ++r) v[r] = (_Float16)acc[4 * p + r];
            *reinterpret_cast<f16x4*>(&outT[(size_t)colg * NN + row]) = v;
        }
        // ---- fused srcdst: wave covers head hstar fully (cols = 32 d's) ----
        const int hstar = colg >> 5;
        const float sv = attn_src[hstar * HD + il];
        const float dv = attn_dst[hstar * HD + il];
        float ps[16], pd[16];
#pragma unroll
        for (int r = 0; r < 16; ++r) { ps[r] = acc[r] * sv; pd[r] = acc[r] * dv; }
#pragma unroll
        for (int m = 1; m <= 16; m <<= 1) {
#pragma unroll
            for (int r = 0; r < 16; ++r) {
                ps[r] += __shfl_xor(ps[r], m);
                pd[r] += __shfl_xor(pd[r], m);
            }
        }
        if (il == 0) {
#pragma unroll
            for (int r = 0; r < 16; ++r) {
                const int row = m0 + wr + (r & 3) + 8 * (r >> 2) + 4 * g;
                asrc[row * NH + hstar] = ps[r];
                adstT[(size_t)hstar * NN + row] = pd[r] * 1.44269504089f;
            }
        }
    } else {
        const float bs = bias1[colg];
#pragma unroll
        for (int r = 0; r < 16; ++r) {
            const int row = m0 + wr + (r & 3) + 8 * (r >> 2) + 4 * g;
            outF[(size_t)row * CALL + colg] = acc[r] + bs;
        }
    }
}

// ---------------------------------------------------------------------------
// gemm2: final GEMM (K=384), K-SPLIT 8-wave blocks as gemm01.
// A=hsum (f16, staged directly), + bias + exact GELU.
// ---------------------------------------------------------------------------
__global__ __launch_bounds__(512) void gemm2(
    const _Float16* __restrict__ A16, const float* __restrict__ B,
    const float* __restrict__ bias, float* __restrict__ outF)
{
    __shared__ __align__(16) char smem[17408];
    _Float16 (*As)[68] = (_Float16(*)[68])(smem);
    _Float16 (*Bs)[68] = (_Float16(*)[68])(smem + 8704);
    float* red = (float*)smem;

    const int t = threadIdx.x;
    const int w = t >> 6, l = t & 63, g = l >> 5, il = l & 31;
    const int q = w & 3, kg = w >> 2;
    const int m0 = blockIdx.x * 64, n0 = blockIdx.y * 64;
    const int wr = (q >> 1) * 32, wc = (q & 1) * 32;
    const int ti = t >> 3, seg = t & 7;
    const int Kdim = 384;

    f32x16 acc;
#pragma unroll
    for (int r = 0; r < 16; ++r) acc[r] = 0.f;

#pragma unroll 1
    for (int ss = 0; ss < 6; ++ss) {
        const int kk = ss * 64;
        __syncthreads();
        {
            const uint4 v = *reinterpret_cast<const uint4*>(A16 + (size_t)(m0 + ti) * Kdim + kk + seg * 8);
            *reinterpret_cast<uint2*>(&As[ti][seg * 8])     = make_uint2(v.x, v.y);
            *reinterpret_cast<uint2*>(&As[ti][seg * 8 + 4]) = make_uint2(v.z, v.w);
        }
        {
            const float* Bp = B + (size_t)(n0 + ti) * Kdim + kk + seg * 8;
            float4 v0 = *reinterpret_cast<const float4*>(Bp);
            float4 v1 = *reinterpret_cast<const float4*>(Bp + 4);
            f16x4 lo = {(_Float16)v0.x, (_Float16)v0.y, (_Float16)v0.z, (_Float16)v0.w};
            f16x4 hi = {(_Float16)v1.x, (_Float16)v1.y, (_Float16)v1.z, (_Float16)v1.w};
            *reinterpret_cast<f16x4*>(&Bs[ti][seg * 8])     = lo;
            *reinterpret_cast<f16x4*>(&Bs[ti][seg * 8 + 4]) = hi;
        }
        __syncthreads();
#pragma unroll
        for (int kc = 0; kc < 4; ++kc) {
            f16x4 af = *reinterpret_cast<const f16x4*>(&As[wr + il][kg * 32 + kc * 8 + 4 * g]);
            f16x4 bf = *reinterpret_cast<const f16x4*>(&Bs[wc + il][kg * 32 + kc * 8 + 4 * g]);
            acc = mfma8f16(af, bf, acc);
        }
    }

    __syncthreads();
    if (kg == 1) {
#pragma unroll
        for (int r = 0; r < 16; ++r) red[(q * 16 + r) * 64 + l] = acc[r];
    }
    __syncthreads();
    if (kg != 0) return;
#pragma unroll
    for (int r = 0; r < 16; ++r) acc[r] += red[(q * 16 + r) * 64 + l];

    const int colg = n0 + wc + il;
    const float bs = bias[colg];
#pragma unroll
    for (int r = 0; r < 16; ++r) {
        const int row = m0 + wr + (r & 3) + 8 * (r >> 2) + 4 * g;
        float vv = acc[r] + bs;
        vv = 0.5f * vv * (1.0f + erff(vv * 0.70710678118f));
        outF[(size_t)row * CALL + colg] = vv;
    }
}

// ---------------------------------------------------------------------------
// attn6: block = 32-row band x 3 heads, 1024 threads = 16 waves (4/SIMD).
// (unchanged from round 7)
// ---------------------------------------------------------------------------
__global__ __launch_bounds__(1024, 4) void attn6(
    const float* __restrict__ adj, const _Float16* __restrict__ hT,
    const float* __restrict__ asrc, const float* __restrict__ adstT,
    const float* __restrict__ eW, const float* __restrict__ eb,
    const float* __restrict__ res, _Float16* __restrict__ hsum)
{
    __shared__ __align__(16) char smem[55296];
    const int t = threadIdx.x;
    const int w = t >> 6, l = t & 63, g = l >> 5, il = l & 31;
    const int band = blockIdx.x & 63, hg = blockIdx.x >> 6;
    const int i0 = band * 32, h0 = hg * 3, c0 = hg * 96;

    float* adst_s = (float*)(smem + w * 1536);
    float* red    = (float*)smem;
    float* dsum_s = (float*)(smem + 49152);

    const float LOG2E = 1.44269504089f;
    float base_h[3], eWr[3];
#pragma unroll
    for (int hh = 0; hh < 3; ++hh) {
        base_h[hh] = (asrc[(size_t)(i0 + il) * NH + h0 + hh] + eb[h0 + hh]) * LOG2E;
        eWr[hh] = eW[h0 + hh] * LOG2E;
    }

    const int jbase = w * 128;
#pragma unroll
    for (int p = 0; p < 6; ++p) {
        const int idx = p * 64 + l;
        adst_s[idx] = adstT[(size_t)(h0 + (idx >> 7)) * NN + jbase + (idx & 127)];
    }

    f32x16 acc[3];
#pragma unroll
    for (int hh = 0; hh < 3; ++hh)
#pragma unroll
        for (int r = 0; r < 16; ++r) acc[hh][r] = 0.f;
    float dsum[3] = {0.f, 0.f, 0.f};

    const _Float16* hbase = hT  + (size_t)(c0 + il) * NN + jbase + 16 * g;
    const float*    abase = adj + (size_t)(i0 + il) * NN + jbase + 16 * g;

    float4 ajc[4], ajn[4];
#pragma unroll
    for (int p = 0; p < 4; ++p)
        ajc[p] = *reinterpret_cast<const float4*>(abase + 4 * p);

#pragma unroll 1
    for (int tl = 0; tl < 4; ++tl) {
        const int jo = tl * 32;
        if (tl < 3) {
#pragma unroll
            for (int p = 0; p < 4; ++p)
                ajn[p] = *reinterpret_cast<const float4*>(abase + jo + 32 + 4 * p);
        }
#pragma unroll
        for (int hh = 0; hh < 3; ++hh) {
            const _Float16* hp = hbase + (size_t)(hh * 32) * NN + jo;
            const uint4 hA = *reinterpret_cast<const uint4*>(hp);
            const uint4 hB = *reinterpret_cast<const uint4*>(hp + 8);
#pragma unroll
            for (int ks = 0; ks < 4; ++ks) {
                const float4 a4 = ajc[ks];
                const float4 ad = *reinterpret_cast<const float4*>(
                    &adst_s[hh * 128 + jo + 16 * g + 4 * ks]);
                f16x4 ef;
#pragma unroll
                for (int jj = 0; jj < 4; ++jj) {
                    const float ajv = (&a4.x)[jj];
                    float tt = fmaf(ajv, eWr[hh], base_h[hh] + (&ad.x)[jj]);
                    tt = fmaxf(tt, 0.2f * tt);
                    const float ee = ajv > 0.f ? exp2f(tt) : 0.f;
                    dsum[hh] += ee;
                    ef[jj] = (_Float16)ee;
                }
                const uint2 hu = (ks == 0) ? make_uint2(hA.x, hA.y)
                               : (ks == 1) ? make_uint2(hA.z, hA.w)
                               : (ks == 2) ? make_uint2(hB.x, hB.y)
                                           : make_uint2(hB.z, hB.w);
                acc[hh] = mfma8f16(ef, u2f(hu), acc[hh]);
            }
        }
#pragma unroll
        for (int p = 0; p < 4; ++p) ajc[p] = ajn[p];
    }

    __syncthreads();
#pragma unroll
    for (int hh = 0; hh < 3; ++hh) {
        const float dtot = dsum[hh] + __shfl_xor(dsum[hh], 32);
        if (g == 0) dsum_s[(w * 3 + hh) * 32 + il] = dtot;
    }
    if (w < 4) {
#pragma unroll
        for (int hh = 0; hh < 3; ++hh)
#pragma unroll
            for (int reg = 0; reg < 16; ++reg)
                red[((w * 3 + hh) * 16 + reg) * 64 + l] = acc[hh][reg];
    }
    __syncthreads();
    if (w >= 4 && w < 8) {
#pragma unroll
        for (int hh = 0; hh < 3; ++hh)
#pragma unroll
            for (int reg = 0; reg < 16; ++reg)
                red[(((w - 4) * 3 + hh) * 16 + reg) * 64 + l] += acc[hh][reg];
    }
    __syncthreads();
    if (w >= 8 && w < 12) {
#pragma unroll
        for (int hh = 0; hh < 3; ++hh)
#pragma unroll
            for (int reg = 0; reg < 16; ++reg)
                red[(((w - 8) * 3 + hh) * 16 + reg) * 64 + l] += acc[hh][reg];
    }
    __syncthreads();
    if (w >= 12) {
#pragma unroll
        for (int hh = 0; hh < 3; ++hh)
#pragma unroll
            for (int reg = 0; reg < 16; ++reg)
                red[(((w - 12) * 3 + hh) * 16 + reg) * 64 + l] += acc[hh][reg];
    }
    __syncthreads();

    {
        const int reg = w;
        const int row_off = (reg & 3) + 8 * (reg >> 2) + 4 * g;
        const int row = i0 + row_off;
#pragma unroll
        for (int hh = 0; hh < 3; ++hh) {
            float v = 0.f, d = 0.f;
#pragma unroll
            for (int p = 0; p < 4; ++p)
                v += red[((p * 3 + hh) * 16 + reg) * 64 + l];
#pragma unroll
            for (int ww = 0; ww < 16; ++ww)
                d += dsum_s[(ww * 3 + hh) * 32 + row_off];
            const int col = (h0 + hh) * 32 + il;
            hsum[(size_t)row * CALL + col] = (_Float16)(v / d + res[(size_t)row * CALL + col]);
        }
    }
}

extern "C" void kernel_launch(void* const* d_in, const int* in_sizes, int n_in,
                              void* d_out, int out_size, void* d_ws, size_t ws_size,
                              hipStream_t stream)
{
    const float* x        = (const float*)d_in[0];
    const float* adj      = (const float*)d_in[1];
    const float* W        = (const float*)d_in[2];
    const float* attn_src = (const float*)d_in[3];
    const float* attn_dst = (const float*)d_in[4];
    const float* edge_W   = (const float*)d_in[5];
    const float* edge_b   = (const float*)d_in[6];
    const float* res_W    = (const float*)d_in[7];
    const float* res_b    = (const float*)d_in[8];
    const float* fus_W    = (const float*)d_in[9];
    const float* fus_b    = (const float*)d_in[10];
    float* out = (float*)d_out;

    char* ws = (char*)d_ws;
    size_t off = 0;
    auto alloc = [&](size_t bytes) { void* p = ws + off; off = (off + bytes + 255) & ~(size_t)255; return p; };
    _Float16* hT    = (_Float16*)alloc((size_t)CALL * NN * 2);
    float*    res   = (float*)alloc((size_t)NN * CALL * 4);
    float*    asrc  = (float*)alloc((size_t)NN * NH * 4);
    float*    adstT = (float*)alloc((size_t)NH * NN * 4);
    _Float16* hsum  = (_Float16*)alloc((size_t)NN * CALL * 2);
    (void)ws_size;

    gemm01<<<dim3(32, 6, 2), dim3(512), 0, stream>>>(x, W, res_W, res_b, attn_src, attn_dst, hT, res, asrc, adstT);
    attn6<<<256, dim3(1024), 0, stream>>>(adj, hT, asrc, adstT, edge_W, edge_b, res, hsum);
    gemm2<<<dim3(32, 6), dim3(512), 0, stream>>>(hsum, fus_W, fus_b, out);
}